// Round 7
// baseline (3245.727 us; speedup 1.0000x reference)
//
#include <hip/hip_runtime.h>

#define V_   50000
#define OOV_ 100
#define VO_  50100
#define E_   128
#define HE_  256
#define HD_  256
#define B_   32
#define S_   256
#define T_   16

typedef _Float16 h2_t __attribute__((ext_vector_type(2)));
typedef __attribute__((ext_vector_type(8))) short bfrag_t;
typedef __attribute__((ext_vector_type(4))) float f32x4;
typedef unsigned short ushort_t;

union U32H2 { unsigned u; h2_t h; };
union FRAG  { uint4 u; bfrag_t s; };

static __device__ __forceinline__ float bf2f(unsigned short b) {
  return __uint_as_float(((unsigned)b) << 16);
}
static __device__ __forceinline__ unsigned short f2bf(float f) {
  unsigned u = __float_as_uint(f);
  unsigned r = (u + 0x7fffu + ((u >> 16) & 1u)) >> 16;
  return (unsigned short)r;
}
static __device__ __forceinline__ float sigm(float x) { return 1.f / (1.f + expf(-x)); }
static __device__ __forceinline__ float fast_sigm(float z) {
  float e = __builtin_amdgcn_exp2f(-1.442695041f * z);
  return __builtin_amdgcn_rcpf(1.f + e);
}
static __device__ __forceinline__ float fast_tanh(float z) {
  float e = __builtin_amdgcn_exp2f(-2.885390082f * z);
  return 2.f * __builtin_amdgcn_rcpf(1.f + e) - 1.f;
}

static __device__ __forceinline__ float dot2u(unsigned upair, unsigned hpairv, float acc) {
  U32H2 a; a.u = upair;
  U32H2 b; b.u = hpairv;
#if __has_builtin(__builtin_amdgcn_fdot2)
  return __builtin_amdgcn_fdot2(a.h, b.h, acc, false);
#else
  acc = fmaf((float)a.h.x, (float)b.h.x, acc);
  return fmaf((float)a.h.y, (float)b.h.y, acc);
#endif
}

// ================= generic bf16 MFMA GEMM (+optional fused row-sum) =================
// C[M,ldC] = act(A[M,K]@Bt^T + bias); A row-major k-contig bf16; Bt [N][K] bf16.
// act: 0 none, 1 tanh, 2 exp. Cbf!=null -> bf16 out. rsum!=null -> atomicAdd row sums.
__global__ __launch_bounds__(256) void mfma_gemm(
    const ushort_t* __restrict__ A, const ushort_t* __restrict__ Bt,
    const float* __restrict__ bias, float* __restrict__ C, ushort_t* __restrict__ Cbf,
    float* __restrict__ rsum, int M, int N, int K, int ldC, int act)
{
  const int w = threadIdx.x >> 6, lane = threadIdx.x & 63;
  const int m0 = blockIdx.y * 64 + w * 16;
  const int n0 = blockIdx.x * 64;
  const int l16 = lane & 15, lq = lane >> 4;
  f32x4 acc[4] = {f32x4{0,0,0,0}, f32x4{0,0,0,0}, f32x4{0,0,0,0}, f32x4{0,0,0,0}};
  for (int k0 = 0; k0 < K; k0 += 32) {
    FRAG a;
    a.u = *(const uint4*)(A + (size_t)(m0 + l16) * K + k0 + lq * 8);
#pragma unroll
    for (int ns = 0; ns < 4; ns++) {
      int n = n0 + ns * 16 + l16;
      int nc = n < N ? n : N - 1;
      FRAG bf;
      bf.u = *(const uint4*)(Bt + (size_t)nc * K + k0 + lq * 8);
      acc[ns] = __builtin_amdgcn_mfma_f32_16x16x32_bf16(a.s, bf.s, acc[ns], 0, 0, 0);
    }
  }
  float bv[4];
#pragma unroll
  for (int ns = 0; ns < 4; ns++) {
    int col = n0 + ns * 16 + l16;
    bv[ns] = (bias && col < N) ? bias[col] : 0.f;
  }
#pragma unroll
  for (int r = 0; r < 4; r++) {
    int row = m0 + lq * 4 + r;   // C/D: col=lane&15, row=(lane>>4)*4+reg
    float part = 0.f;
#pragma unroll
    for (int ns = 0; ns < 4; ns++) {
      int col = n0 + ns * 16 + l16;
      if (col < N) {
        float v = acc[ns][r] + bv[ns];
        if (act == 1) v = tanhf(v);
        else if (act == 2) v = expf(v);
        if (Cbf) Cbf[(size_t)row * ldC + col] = f2bf(v);
        else     C[(size_t)row * ldC + col] = v;
        part += v;
      }
    }
    if (rsum) {
      part += __shfl_xor(part, 1);
      part += __shfl_xor(part, 2);
      part += __shfl_xor(part, 4);
      part += __shfl_xor(part, 8);
      if (l16 == 0) atomicAdd(&rsum[row], part);
    }
  }
}

// ================= prep: all weight transposes / packs / embeds, role-dispatched ==========
static __device__ __forceinline__ void tconv_tile(
    const float* __restrict__ W, ushort_t* __restrict__ Wt, int K, int N,
    int kb, int nb, int tid, ushort_t (*tile)[33])
{
  const int tx = tid & 31, ty = tid >> 5;
#pragma unroll
  for (int p = 0; p < 4; p++) {
    int k = kb + ty + p * 8, n = nb + tx;
    if (k < K && n < N) tile[ty + p * 8][tx] = f2bf(W[(size_t)k * N + n]);
  }
  __syncthreads();
#pragma unroll
  for (int p = 0; p < 4; p++) {
    int n = nb + ty + p * 8, k = kb + tx;
    if (k < K && n < N) Wt[(size_t)n * K + k] = tile[tx][ty + p * 8];
  }
}
static __device__ __forceinline__ void packU2_one(
    const float* __restrict__ U, unsigned* __restrict__ out, int i)
{
  int p = i >> 10, col = i & 1023;
  U32H2 cv; cv.h = h2_t{(_Float16)U[(size_t)(2 * p) * 1024 + col],
                        (_Float16)U[(size_t)(2 * p + 1) * 1024 + col]};
  out[i] = cv.u;
}

__global__ __launch_bounds__(256) void prep_kernel(
    const float* __restrict__ Wenc, const float* __restrict__ Wdec,
    const float* __restrict__ We2d, const float* __restrict__ Wattn,
    const float* __restrict__ Wout, const float* __restrict__ Wcopy,
    const float* __restrict__ Uenc, const float* __restrict__ Udec,
    const int* __restrict__ x, const int* __restrict__ decx, const float* __restrict__ emb,
    ushort_t* WencT, ushort_t* WdecT, ushort_t* We2dT, ushort_t* WattnT,
    ushort_t* WoutT, ushort_t* WcopyT, unsigned* Upk2E, unsigned* Upk2D,
    ushort_t* xembbf, ushort_t* dembbf)
{
  __shared__ ushort_t tile[32][33];
  int blk = blockIdx.x;
  const int tid = threadIdx.x;
  if (blk < 128) { tconv_tile(Wenc, WencT, 128, 1024, (blk >> 5) * 32, (blk & 31) * 32, tid, tile); return; }
  blk -= 128;
  if (blk < 128) { tconv_tile(Wdec, WdecT, 128, 1024, (blk >> 5) * 32, (blk & 31) * 32, tid, tile); return; }
  blk -= 128;
  if (blk < 64)  { tconv_tile(We2d, We2dT, 256, 256, (blk >> 3) * 32, (blk & 7) * 32, tid, tile); return; }
  blk -= 64;
  if (blk < 64)  { tconv_tile(Wattn, WattnT, 256, 256, (blk >> 3) * 32, (blk & 7) * 32, tid, tile); return; }
  blk -= 64;
  if (blk < 128) { tconv_tile(Wout, WoutT, 512, 256, (blk >> 3) * 32, (blk & 7) * 32, tid, tile); return; }
  blk -= 128;
  if (blk < 64)  { tconv_tile(Wcopy, WcopyT, 256, 256, (blk >> 3) * 32, (blk & 7) * 32, tid, tile); return; }
  blk -= 64;
  if (blk < 512) { packU2_one(Uenc, Upk2E, blk * 256 + tid); return; }
  blk -= 512;
  if (blk < 512) { packU2_one(Udec, Upk2D, blk * 256 + tid); return; }
  blk -= 512;
  if (blk < 4096) {
    int i = blk * 256 + tid, r = i >> 7;
    xembbf[i] = f2bf(emb[(size_t)x[r] * E_ + (i & 127)]);
    return;
  }
  blk -= 4096;
  {
    int i = blk * 256 + tid, r = i >> 7;
    dembbf[i] = f2bf(emb[(size_t)decx[r] * E_ + (i & 127)]);
  }
}

// ================= LSTM v11: lstm10 structure, VGPR-resident U (no AGPR demotion) ==========
// Register-pressure fix: U split 8 pair-rows in named VGPR vars (64 dw) +
// 4 pair-rows in LDS (lstm10's conflict-free layout) + 4 pair-rows STREAMED
// from L2 each step (loop-invariant values; opaque asm offset defeats
// hoisting so loads stay per-iteration normal IR loads -> compiler-managed
// vmcnt).  Demand ~125 regs < 128 budget -> everything in VGPRs.
// Blocks >= 32 (decoder dispatch): Wgen transpose role.
#define DOT8(u0, u1, hpi)                \
  acc[0] = dot2u(u0.x, hpi, acc[0]);     \
  acc[1] = dot2u(u0.y, hpi, acc[1]);     \
  acc[2] = dot2u(u0.z, hpi, acc[2]);     \
  acc[3] = dot2u(u0.w, hpi, acc[3]);     \
  acc[4] = dot2u(u1.x, hpi, acc[4]);     \
  acc[5] = dot2u(u1.y, hpi, acc[5]);     \
  acc[6] = dot2u(u1.z, hpi, acc[6]);     \
  acc[7] = dot2u(u1.w, hpi, acc[7]);

__global__ __launch_bounds__(1024, 4) void lstm11(
    const float* __restrict__ Xpre, const unsigned* __restrict__ Upk2,
    const float* __restrict__ h0, const float* __restrict__ c0,
    ushort_t* __restrict__ outH, float* __restrict__ hN, float* __restrict__ cN,
    ushort_t* __restrict__ hNbf, ushort_t* __restrict__ cNbf,
    int steps, const float* __restrict__ Wg, ushort_t* __restrict__ WgT)
{
  __shared__ unsigned ldsU[8 * 4096];   // 128KB: pairs kq*16+{8..11}, [idx 0..7][tid*4]
  __shared__ float    zpart[4 * 1028];  //  16,448 B
  __shared__ unsigned hpair[8 * 20];    //     640 B
  const int tid = threadIdx.x;

  if (blockIdx.x >= 32) {
    // --- Wgen transpose role (runs on idle CUs during decoder) ---
    ushort_t* tile = (ushort_t*)ldsU;    // [64][65]
    int tb = blockIdx.x - 32;            // 3128 tiles: 4 k-tiles x 782 n-tiles
    int kb = (tb & 3) * 64, nb = (tb >> 2) * 64;
#pragma unroll
    for (int p = 0; p < 4; p++) {
      int i = p * 1024 + tid, k = i >> 6, n = i & 63;
      if (nb + n < V_) tile[k * 65 + n] = f2bf(Wg[(size_t)(kb + k) * V_ + nb + n]);
    }
    __syncthreads();
#pragma unroll
    for (int p = 0; p < 4; p++) {
      int i = p * 1024 + tid, n = i >> 6, k = i & 63;
      if (nb + n < V_) WgT[(size_t)(nb + n) * 256 + kb + k] = tile[k * 65 + n];
    }
    return;
  }

  const int b = blockIdx.x;
  const int jg = tid >> 3, kq = tid & 7;
  const unsigned* ubase = Upk2 + jg * 8;

  // pairs kq*16 + {0..7}: 16 named uint4 VGPR vars (64 dwords)
  uint4 u0  = *(const uint4*)(ubase + (kq * 16 + 0) * 1024);
  uint4 u1  = *(const uint4*)(ubase + (kq * 16 + 0) * 1024 + 4);
  uint4 u2  = *(const uint4*)(ubase + (kq * 16 + 1) * 1024);
  uint4 u3  = *(const uint4*)(ubase + (kq * 16 + 1) * 1024 + 4);
  uint4 u4  = *(const uint4*)(ubase + (kq * 16 + 2) * 1024);
  uint4 u5  = *(const uint4*)(ubase + (kq * 16 + 2) * 1024 + 4);
  uint4 u6  = *(const uint4*)(ubase + (kq * 16 + 3) * 1024);
  uint4 u7  = *(const uint4*)(ubase + (kq * 16 + 3) * 1024 + 4);
  uint4 u8  = *(const uint4*)(ubase + (kq * 16 + 4) * 1024);
  uint4 u9  = *(const uint4*)(ubase + (kq * 16 + 4) * 1024 + 4);
  uint4 u10 = *(const uint4*)(ubase + (kq * 16 + 5) * 1024);
  uint4 u11 = *(const uint4*)(ubase + (kq * 16 + 5) * 1024 + 4);
  uint4 u12 = *(const uint4*)(ubase + (kq * 16 + 6) * 1024);
  uint4 u13 = *(const uint4*)(ubase + (kq * 16 + 6) * 1024 + 4);
  uint4 u14 = *(const uint4*)(ubase + (kq * 16 + 7) * 1024);
  uint4 u15 = *(const uint4*)(ubase + (kq * 16 + 7) * 1024 + 4);
  // pairs kq*16 + {8..11} -> LDS, per-thread-contiguous (conflict-free)
  {
    unsigned* myst = &ldsU[tid * 4];
#pragma unroll
    for (int i = 0; i < 4; i++) {
      int p = kq * 16 + 8 + i;
      uint4 q0 = *(const uint4*)(ubase + p * 1024);
      uint4 q1 = *(const uint4*)(ubase + p * 1024 + 4);
      *(uint4*)(myst + (2 * i) * 4096)     = q0;
      *(uint4*)(myst + (2 * i + 1) * 4096) = q1;
    }
  }
  // pairs kq*16 + {12..15}: streamed from L2 every step
  const unsigned* gbase = ubase + (kq * 16 + 12) * 1024;

  float c = 0.f, hcur = 0.f;
  if (tid < 256) {
    c    = c0 ? c0[b * 256 + tid] : 0.f;
    hcur = h0 ? h0[b * 256 + tid] : 0.f;
  }
  if (tid < 128) {
    float a  = h0 ? h0[b * 256 + 2 * tid] : 0.f;
    float b2 = h0 ? h0[b * 256 + 2 * tid + 1] : 0.f;
    U32H2 cv; cv.h = h2_t{(_Float16)a, (_Float16)b2};
    hpair[(tid >> 4) * 20 + (tid & 15)] = cv.u;   // pair P: addr (P>>4)*20 + (P&15)
  }
  __syncthreads();

  const float* xp = Xpre + (size_t)b * steps * 1024;
  const unsigned* myld = &ldsU[tid * 4];

  for (int t = 0; t < steps; t++) {
    // stream pairs 12..15 (values loop-invariant; opaque offset defeats hoist)
    unsigned goff = 0;
    asm volatile("" : "+v"(goff));
    const unsigned* gp = gbase + goff;
    uint4 g0 = *(const uint4*)(gp);
    uint4 g1 = *(const uint4*)(gp + 4);
    uint4 g2 = *(const uint4*)(gp + 1024);
    uint4 g3 = *(const uint4*)(gp + 1024 + 4);
    uint4 g4 = *(const uint4*)(gp + 2048);
    uint4 g5 = *(const uint4*)(gp + 2048 + 4);
    uint4 g6 = *(const uint4*)(gp + 3072);
    uint4 g7 = *(const uint4*)(gp + 3072 + 4);

    float acc[8] = {0.f, 0.f, 0.f, 0.f, 0.f, 0.f, 0.f, 0.f};
    {
      uint4 hA = *(const uint4*)&hpair[kq * 20];
      DOT8(u0, u1, hA.x)   DOT8(u2, u3, hA.y)
      DOT8(u4, u5, hA.z)   DOT8(u6, u7, hA.w)
    }
    {
      uint4 hB = *(const uint4*)&hpair[kq * 20 + 4];
      DOT8(u8, u9, hB.x)   DOT8(u10, u11, hB.y)
      DOT8(u12, u13, hB.z) DOT8(u14, u15, hB.w)
    }
    {
      uint4 hC = *(const uint4*)&hpair[kq * 20 + 8];
      unsigned hh[4] = {hC.x, hC.y, hC.z, hC.w};
#pragma unroll
      for (int r = 0; r < 4; r++) {
        uint4 l0 = *(const uint4*)(myld + (2 * r) * 4096);
        uint4 l1 = *(const uint4*)(myld + (2 * r + 1) * 4096);
        unsigned hpi = hh[r];
        DOT8(l0, l1, hpi)
      }
    }
    {
      uint4 hD = *(const uint4*)&hpair[kq * 20 + 12];
      DOT8(g0, g1, hD.x)   DOT8(g2, g3, hD.y)
      DOT8(g4, g5, hD.z)   DOT8(g6, g7, hD.w)
    }
    // phase-2 x-preacts (consumed after barrier A)
    float xq0 = 0.f, xq1 = 0.f, xq2 = 0.f, xq3 = 0.f;
    if (tid < 256) {
      const float* xr = xp + (size_t)t * 1024 + tid;
      xq0 = xr[0]; xq1 = xr[256]; xq2 = xr[512]; xq3 = xr[768];
    }
#pragma unroll
    for (int g = 0; g < 8; g++) acc[g] += __shfl_xor(acc[g], 1);
    if ((kq & 1) == 0) {
      int r = kq >> 1;
      *(float4*)&zpart[r * 1028 + jg * 8]     = make_float4(acc[0], acc[1], acc[2], acc[3]);
      *(float4*)&zpart[r * 1028 + jg * 8 + 4] = make_float4(acc[4], acc[5], acc[6], acc[7]);
    }
    __syncthreads();   // A: zpart ready
    if (tid < 256) {
      float zi = xq0, zf = xq1, zg = xq2, zo = xq3;
#pragma unroll
      for (int r = 0; r < 4; r++) {
        const float* zr = &zpart[r * 1028 + tid];
        zi += zr[0]; zf += zr[256]; zg += zr[512]; zo += zr[768];
      }
      float ai = fast_sigm(zi), af = fast_sigm(zf);
      float ag = fast_tanh(zg), ao = fast_sigm(zo);
      c = fmaf(af, c, ai * ag);
      hcur = ao * fast_tanh(c);
      outH[((size_t)b * steps + t) * 256 + tid] = f2bf(hcur);
      float hnx = __shfl_down(hcur, 1);
      if ((tid & 1) == 0) {
        U32H2 cv; cv.h = h2_t{(_Float16)hcur, (_Float16)hnx};
        int P = tid >> 1;
        hpair[(P >> 4) * 20 + (P & 15)] = cv.u;
      }
    }
    __syncthreads();   // B: hpair(t+1) ready, zpart(t) consumed
  }
  if (tid < 256) {
    if (hN)   hN[b * 256 + tid] = hcur;
    if (cN)   cN[b * 256 + tid] = c;
    if (hNbf) hNbf[b * 256 + tid] = f2bf(hcur);
    if (cNbf) cNbf[b * 256 + tid] = f2bf(c);
  }
}

// ================= attention: one block per (b,t); writes bf16 catb directly ==========
__global__ __launch_bounds__(256) void attn_kernel(
    const float* __restrict__ dq, const ushort_t* __restrict__ enc,
    const int* __restrict__ x_len, const ushort_t* __restrict__ dec,
    ushort_t* __restrict__ catb)
{
  __shared__ float q[256];
  __shared__ float eb[32][256];
  __shared__ float sc[256];
  __shared__ float red[8];
  const int bt = blockIdx.x, tid = threadIdx.x;
  const int b = bt >> 4;
  q[tid] = dq[(size_t)bt * 256 + tid];
  const int len = x_len[b];
  const unsigned* encu = (const unsigned*)(enc + (size_t)b * S_ * 256);
  __syncthreads();
  const int s_loc = tid >> 3, hb = (tid & 7) * 32;
  for (int cch = 0; cch < 8; cch++) {
#pragma unroll
    for (int qv = 0; qv < 16; qv++) {
      int idx = qv * 256 + tid;
      unsigned u = encu[cch * 4096 + idx];
      int row = idx >> 7, cp2 = (idx & 127) * 2;
      eb[row][cp2]     = bf2f((unsigned short)(u & 0xffffu));
      eb[row][cp2 + 1] = bf2f((unsigned short)(u >> 16));
    }
    __syncthreads();
    float p = 0.f;
#pragma unroll
    for (int h = 0; h < 32; h++) p = fmaf(q[hb + h], eb[s_loc][hb + h], p);
    p += __shfl_down(p, 4, 8);
    p += __shfl_down(p, 2, 8);
    p += __shfl_down(p, 1, 8);
    if ((tid & 7) == 0) sc[cch * 32 + s_loc] = p;
    __syncthreads();
  }
  float my = (tid < len) ? sc[tid] : -1e30f;
  float m = my;
#pragma unroll
  for (int o = 32; o >= 1; o >>= 1) m = fmaxf(m, __shfl_xor(m, o));
  if ((tid & 63) == 0) red[tid >> 6] = m;
  __syncthreads();
  float bm = fmaxf(fmaxf(red[0], red[1]), fmaxf(red[2], red[3]));
  float e = expf(my - bm);
  float s = e;
#pragma unroll
  for (int o = 32; o >= 1; o >>= 1) s += __shfl_xor(s, o);
  if ((tid & 63) == 0) red[4 + (tid >> 6)] = s;
  __syncthreads();
  float tot = red[4] + red[5] + red[6] + red[7];
  sc[tid] = e / tot;
  __syncthreads();
  const ushort_t* encb = enc + (size_t)b * S_ * 256;
  float acc = 0.f;
  for (int s2 = 0; s2 < 256; s2++) acc = fmaf(sc[s2], bf2f(encb[(size_t)s2 * 256 + tid]), acc);
  catb[(size_t)bt * 512 + tid]       = f2bf(acc);                    // ctx half
  catb[(size_t)bt * 512 + 256 + tid] = dec[(size_t)bt * 256 + tid];  // dec half
}

// ================= copy scores: one block per (b,t); attn_out now bf16 ============
__global__ __launch_bounds__(256) void copyseq_kernel(
    const ushort_t* __restrict__ at, const ushort_t* __restrict__ cp,
    const int* __restrict__ x_len, float* __restrict__ cseq)
{
  __shared__ float q[256];
  __shared__ float eb[32][256];
  __shared__ float sc[256];
  const int bt = blockIdx.x, tid = threadIdx.x;
  const int b = bt >> 4;
  q[tid] = bf2f(at[(size_t)bt * 256 + tid]);
  const int len = x_len[b];
  const unsigned* cpu_ = (const unsigned*)(cp + (size_t)b * S_ * 256);
  __syncthreads();
  const int s_loc = tid >> 3, hb = (tid & 7) * 32;
  for (int cch = 0; cch < 8; cch++) {
#pragma unroll
    for (int qv = 0; qv < 16; qv++) {
      int idx = qv * 256 + tid;
      unsigned u = cpu_[cch * 4096 + idx];
      int row = idx >> 7, cp2 = (idx & 127) * 2;
      eb[row][cp2]     = bf2f((unsigned short)(u & 0xffffu));
      eb[row][cp2 + 1] = bf2f((unsigned short)(u >> 16));
    }
    __syncthreads();
    float p = 0.f;
#pragma unroll
    for (int h = 0; h < 32; h++) p = fmaf(q[hb + h], eb[s_loc][hb + h], p);
    p += __shfl_down(p, 4, 8);
    p += __shfl_down(p, 2, 8);
    p += __shfl_down(p, 1, 8);
    if ((tid & 7) == 0) sc[cch * 32 + s_loc] = p;
    __syncthreads();
  }
  cseq[(size_t)bt * 256 + tid] = (tid < len) ? expf(sc[tid]) : 0.f;
}

// ================= small kernels =================
// one block per bt-row; pads own row's OOV cells, then scatter-adds + row sum
__global__ __launch_bounds__(256) void scatter_kernel(
    const float* __restrict__ cseq, const int* __restrict__ xoov,
    float* __restrict__ out, float* __restrict__ rsum)
{
  __shared__ float red[4];
  const int bt = blockIdx.x, tid = threadIdx.x, b = bt >> 4;
  if (tid < OOV_) out[(size_t)bt * VO_ + V_ + tid] = 1e-10f;   // fused pad
  __syncthreads();
  float v = cseq[(size_t)bt * 256 + tid];
  if (v != 0.f) atomicAdd(&out[(size_t)bt * VO_ + xoov[b * S_ + tid]], v);
  float s = v;
#pragma unroll
  for (int o = 32; o >= 1; o >>= 1) s += __shfl_xor(s, o);
  if ((tid & 63) == 0) red[tid >> 6] = s;
  __syncthreads();
  if (tid == 0) atomicAdd(&rsum[bt], red[0] + red[1] + red[2] + red[3]);
}
__global__ void rowlog_kernel(const float* __restrict__ rsum, float* __restrict__ rowlog) {
  int i = blockIdx.x * 256 + threadIdx.x;
  if (i < B_ * T_) rowlog[i] = logf(rsum[i] + 1e-8f);  // +1e-8 = 100 pad cells * 1e-10
}
__global__ void finalize_kernel(float* __restrict__ out, const float* __restrict__ rowlog) {
  size_t i = (size_t)blockIdx.x * 256 + threadIdx.x;
  if (i < (size_t)B_ * T_ * VO_) {
    int bt = (int)(i / VO_);
    out[i] = logf(out[i]) - rowlog[bt];
  }
}

extern "C" void kernel_launch(void* const* d_in, const int* in_sizes, int n_in,
                              void* d_out, int out_size, void* d_ws, size_t ws_size,
                              hipStream_t stream) {
  const int*   x     = (const int*)d_in[0];
  const int*   xoov  = (const int*)d_in[1];
  const int*   xlen  = (const int*)d_in[2];
  const int*   decx  = (const int*)d_in[3];
  const float* emb   = (const float*)d_in[4];
  const float* Wenc  = (const float*)d_in[5];
  const float* Uenc  = (const float*)d_in[6];
  const float* benc  = (const float*)d_in[7];
  const float* We2d  = (const float*)d_in[8];
  const float* be2d  = (const float*)d_in[9];
  const float* Wdec  = (const float*)d_in[10];
  const float* Udec  = (const float*)d_in[11];
  const float* bdec  = (const float*)d_in[12];
  const float* Wattn = (const float*)d_in[13];
  const float* Wout  = (const float*)d_in[14];
  const float* bout  = (const float*)d_in[15];
  const float* Wgen  = (const float*)d_in[16];
  const float* Wcopy = (const float*)d_in[17];
  const float* bcopy = (const float*)d_in[18];
  float* out = (float*)d_out;
  float* ws  = (float*)d_ws;

  // ---- workspace layout (float offsets), ~47.6 MB ----
  float*    Xenc   = ws + 0;                         // 8,388,608 fl (dead after encoder)
  ushort_t* WgenT  = (ushort_t*)(ws + 0);            // phase2: 12.8M ush (decoder dispatch)
  ushort_t* cp_bf  = (ushort_t*)(ws + 6400000);      // phase2: 2.1M ush
  float*    dqb    = ws + 8388608;
  float*    cseq   = ws + 8781824;
  float*    rsum   = ws + 8912896;                   // 512
  float*    rowlog = ws + 8913408;                   // 512
  ushort_t* Abf    = (ushort_t*)(ws + 8913920);
  ushort_t* catb   = (ushort_t*)(ws + 8979456);
  ushort_t* decObf = (ushort_t*)(ws + 9110528);
  ushort_t* xembbf = (ushort_t*)(ws + 9176064);
  ushort_t* dembbf = (ushort_t*)(ws + 9700352);
  float*    Xdec   = ws + 9733120;
  ushort_t* WencT  = (ushort_t*)(ws + 10257408);
  ushort_t* WdecT  = (ushort_t*)(ws + 10322944);
  ushort_t* We2dT  = (ushort_t*)(ws + 10388480);
  ushort_t* WattnT = (ushort_t*)(ws + 10421248);
  ushort_t* WoutT  = (ushort_t*)(ws + 10454016);
  ushort_t* WcopyT = (ushort_t*)(ws + 10519552);
  unsigned* Upk2E  = (unsigned*)(ws + 10552320);
  unsigned* Upk2D  = (unsigned*)(ws + 10683392);
  ushort_t* encObf = (ushort_t*)(ws + 10814464);
  float*    ehc    = ws + 11863040;                  // unused f32 shadow (kept for safety)
  ushort_t* ehcbf  = (ushort_t*)(ws + 11879424);
  float*    h0c0   = ws + 11887616;

  float* sh  = out + (size_t)B_ * T_ * VO_;
  float* scf = sh + B_ * HD_;

  hipMemsetAsync(rsum, 0, 512 * sizeof(float), stream);

  hipLaunchKernelGGL(prep_kernel, dim3(5952), dim3(256), 0, stream,
                     Wenc, Wdec, We2d, Wattn, Wout, Wcopy, Uenc, Udec, x, decx, emb,
                     WencT, WdecT, We2dT, WattnT, WoutT, WcopyT, Upk2E, Upk2D,
                     xembbf, dembbf);

  hipLaunchKernelGGL(mfma_gemm, dim3(16, 128), dim3(256), 0, stream,
                     xembbf, WencT, benc, Xenc, (ushort_t*)nullptr, (float*)nullptr,
                     B_ * S_, 1024, 128, 1024, 0);
  hipLaunchKernelGGL(mfma_gemm, dim3(16, 8), dim3(256), 0, stream,
                     dembbf, WdecT, bdec, Xdec, (ushort_t*)nullptr, (float*)nullptr,
                     B_ * T_, 1024, 128, 1024, 0);

  // encoder: emits bf16 final states directly (ehcbf = [h | c])
  hipLaunchKernelGGL(lstm11, dim3(32), dim3(1024), 0, stream,
                     Xenc, Upk2E, (const float*)nullptr, (const float*)nullptr,
                     encObf, (float*)nullptr, (float*)nullptr,
                     ehcbf, ehcbf + 32 * 256, S_,
                     (const float*)nullptr, (ushort_t*)nullptr);

  hipLaunchKernelGGL(mfma_gemm, dim3(4, 1), dim3(256), 0, stream,
                     ehcbf, We2dT, be2d, h0c0, (ushort_t*)nullptr, (float*)nullptr,
                     64, 256, 256, 256, 0);

  // decoder + fused Wgen transpose on the idle 224 CUs (Xenc region is dead now)
  hipLaunchKernelGGL(lstm11, dim3(32 + 3128), dim3(1024), 0, stream,
                     Xdec, Upk2D, h0c0, h0c0 + 32 * 256, decObf, sh, scf,
                     (ushort_t*)nullptr, (ushort_t*)nullptr, T_,
                     Wgen, WgenT);

  hipLaunchKernelGGL(mfma_gemm, dim3(4, 8), dim3(256), 0, stream,
                     decObf, WattnT, (const float*)nullptr, dqb, (ushort_t*)nullptr,
                     (float*)nullptr, B_ * T_, 256, 256, 256, 0);
  hipLaunchKernelGGL(attn_kernel, dim3(B_ * T_), dim3(256), 0, stream,
                     dqb, encObf, xlen, decObf, catb);
  hipLaunchKernelGGL(mfma_gemm, dim3(4, 8), dim3(256), 0, stream,
                     catb, WoutT, bout, (float*)nullptr, Abf, (float*)nullptr,
                     B_ * T_, 256, 512, 256, 1);
  hipLaunchKernelGGL(mfma_gemm, dim3(4, 128), dim3(256), 0, stream,
                     encObf, WcopyT, bcopy, (float*)nullptr, cp_bf, (float*)nullptr,
                     B_ * S_, 256, 256, 256, 1);
  hipLaunchKernelGGL(mfma_gemm, dim3(782, 8), dim3(256), 0, stream,
                     Abf, WgenT, (const float*)nullptr, out, (ushort_t*)nullptr, rsum,
                     B_ * T_, V_, 256, VO_, 2);
  hipLaunchKernelGGL(copyseq_kernel, dim3(B_ * T_), dim3(256), 0, stream, Abf, cp_bf, xlen, cseq);
  hipLaunchKernelGGL(scatter_kernel, dim3(512), dim3(256), 0, stream, cseq, xoov, out, rsum);
  hipLaunchKernelGGL(rowlog_kernel, dim3(2), dim3(256), 0, stream, rsum, rowlog);
  hipLaunchKernelGGL(finalize_kernel, dim3((B_ * T_ * VO_ + 255) / 256), dim3(256), 0, stream,
                     out, rowlog);
}

// Round 8
// 1188.369 us; speedup vs baseline: 2.7312x; 2.7312x over previous
//
#include <hip/hip_runtime.h>

#define V_   50000
#define OOV_ 100
#define VO_  50100
#define E_   128
#define HE_  256
#define HD_  256
#define B_   32
#define S_   256
#define T_   16

typedef _Float16 h2_t __attribute__((ext_vector_type(2)));
typedef __attribute__((ext_vector_type(8))) short bfrag_t;
typedef __attribute__((ext_vector_type(4))) float f32x4;
typedef unsigned short ushort_t;

union U32H2 { unsigned u; h2_t h; };
union FRAG  { uint4 u; bfrag_t s; };

static __device__ __forceinline__ float bf2f(unsigned short b) {
  return __uint_as_float(((unsigned)b) << 16);
}
static __device__ __forceinline__ unsigned short f2bf(float f) {
  unsigned u = __float_as_uint(f);
  unsigned r = (u + 0x7fffu + ((u >> 16) & 1u)) >> 16;
  return (unsigned short)r;
}
static __device__ __forceinline__ float sigm(float x) { return 1.f / (1.f + expf(-x)); }
static __device__ __forceinline__ float fast_sigm(float z) {
  float e = __builtin_amdgcn_exp2f(-1.442695041f * z);
  return __builtin_amdgcn_rcpf(1.f + e);
}
static __device__ __forceinline__ float fast_tanh(float z) {
  float e = __builtin_amdgcn_exp2f(-2.885390082f * z);
  return 2.f * __builtin_amdgcn_rcpf(1.f + e) - 1.f;
}

static __device__ __forceinline__ float dot2u(unsigned upair, unsigned hpairv, float acc) {
  U32H2 a; a.u = upair;
  U32H2 b; b.u = hpairv;
#if __has_builtin(__builtin_amdgcn_fdot2)
  return __builtin_amdgcn_fdot2(a.h, b.h, acc, false);
#else
  acc = fmaf((float)a.h.x, (float)b.h.x, acc);
  return fmaf((float)a.h.y, (float)b.h.y, acc);
#endif
}

// ================= generic bf16 MFMA GEMM (+optional fused row-sum) =================
// C[M,ldC] = act(A[M,K]@Bt^T + bias); A row-major k-contig bf16; Bt [N][K] bf16.
// act: 0 none, 1 tanh, 2 exp. Cbf!=null -> bf16 out. rsum!=null -> atomicAdd row sums.
__global__ __launch_bounds__(256) void mfma_gemm(
    const ushort_t* __restrict__ A, const ushort_t* __restrict__ Bt,
    const float* __restrict__ bias, float* __restrict__ C, ushort_t* __restrict__ Cbf,
    float* __restrict__ rsum, int M, int N, int K, int ldC, int act)
{
  const int w = threadIdx.x >> 6, lane = threadIdx.x & 63;
  const int m0 = blockIdx.y * 64 + w * 16;
  const int n0 = blockIdx.x * 64;
  const int l16 = lane & 15, lq = lane >> 4;
  f32x4 acc[4] = {f32x4{0,0,0,0}, f32x4{0,0,0,0}, f32x4{0,0,0,0}, f32x4{0,0,0,0}};
  for (int k0 = 0; k0 < K; k0 += 32) {
    FRAG a;
    a.u = *(const uint4*)(A + (size_t)(m0 + l16) * K + k0 + lq * 8);
#pragma unroll
    for (int ns = 0; ns < 4; ns++) {
      int n = n0 + ns * 16 + l16;
      int nc = n < N ? n : N - 1;
      FRAG bf;
      bf.u = *(const uint4*)(Bt + (size_t)nc * K + k0 + lq * 8);
      acc[ns] = __builtin_amdgcn_mfma_f32_16x16x32_bf16(a.s, bf.s, acc[ns], 0, 0, 0);
    }
  }
  float bv[4];
#pragma unroll
  for (int ns = 0; ns < 4; ns++) {
    int col = n0 + ns * 16 + l16;
    bv[ns] = (bias && col < N) ? bias[col] : 0.f;
  }
#pragma unroll
  for (int r = 0; r < 4; r++) {
    int row = m0 + lq * 4 + r;   // C/D: col=lane&15, row=(lane>>4)*4+reg
    float part = 0.f;
#pragma unroll
    for (int ns = 0; ns < 4; ns++) {
      int col = n0 + ns * 16 + l16;
      if (col < N) {
        float v = acc[ns][r] + bv[ns];
        if (act == 1) v = tanhf(v);
        else if (act == 2) v = expf(v);
        if (Cbf) Cbf[(size_t)row * ldC + col] = f2bf(v);
        else     C[(size_t)row * ldC + col] = v;
        part += v;
      }
    }
    if (rsum) {
      part += __shfl_xor(part, 1);
      part += __shfl_xor(part, 2);
      part += __shfl_xor(part, 4);
      part += __shfl_xor(part, 8);
      if (l16 == 0) atomicAdd(&rsum[row], part);
    }
  }
}

// ================= prep: all weight transposes / packs / embeds, role-dispatched ==========
static __device__ __forceinline__ void tconv_tile(
    const float* __restrict__ W, ushort_t* __restrict__ Wt, int K, int N,
    int kb, int nb, int tid, ushort_t (*tile)[33])
{
  const int tx = tid & 31, ty = tid >> 5;
#pragma unroll
  for (int p = 0; p < 4; p++) {
    int k = kb + ty + p * 8, n = nb + tx;
    if (k < K && n < N) tile[ty + p * 8][tx] = f2bf(W[(size_t)k * N + n]);
  }
  __syncthreads();
#pragma unroll
  for (int p = 0; p < 4; p++) {
    int n = nb + ty + p * 8, k = kb + tx;
    if (k < K && n < N) Wt[(size_t)n * K + k] = tile[tx][ty + p * 8];
  }
}
static __device__ __forceinline__ void packU2_one(
    const float* __restrict__ U, unsigned* __restrict__ out, int i)
{
  int p = i >> 10, col = i & 1023;
  U32H2 cv; cv.h = h2_t{(_Float16)U[(size_t)(2 * p) * 1024 + col],
                        (_Float16)U[(size_t)(2 * p + 1) * 1024 + col]};
  out[i] = cv.u;
}

__global__ __launch_bounds__(256) void prep_kernel(
    const float* __restrict__ Wenc, const float* __restrict__ Wdec,
    const float* __restrict__ We2d, const float* __restrict__ Wattn,
    const float* __restrict__ Wout, const float* __restrict__ Wcopy,
    const float* __restrict__ Uenc, const float* __restrict__ Udec,
    const int* __restrict__ x, const int* __restrict__ decx, const float* __restrict__ emb,
    ushort_t* WencT, ushort_t* WdecT, ushort_t* We2dT, ushort_t* WattnT,
    ushort_t* WoutT, ushort_t* WcopyT, unsigned* Upk2E, unsigned* Upk2D,
    ushort_t* xembbf, ushort_t* dembbf)
{
  __shared__ ushort_t tile[32][33];
  int blk = blockIdx.x;
  const int tid = threadIdx.x;
  if (blk < 128) { tconv_tile(Wenc, WencT, 128, 1024, (blk >> 5) * 32, (blk & 31) * 32, tid, tile); return; }
  blk -= 128;
  if (blk < 128) { tconv_tile(Wdec, WdecT, 128, 1024, (blk >> 5) * 32, (blk & 31) * 32, tid, tile); return; }
  blk -= 128;
  if (blk < 64)  { tconv_tile(We2d, We2dT, 256, 256, (blk >> 3) * 32, (blk & 7) * 32, tid, tile); return; }
  blk -= 64;
  if (blk < 64)  { tconv_tile(Wattn, WattnT, 256, 256, (blk >> 3) * 32, (blk & 7) * 32, tid, tile); return; }
  blk -= 64;
  if (blk < 128) { tconv_tile(Wout, WoutT, 512, 256, (blk >> 3) * 32, (blk & 7) * 32, tid, tile); return; }
  blk -= 128;
  if (blk < 64)  { tconv_tile(Wcopy, WcopyT, 256, 256, (blk >> 3) * 32, (blk & 7) * 32, tid, tile); return; }
  blk -= 64;
  if (blk < 512) { packU2_one(Uenc, Upk2E, blk * 256 + tid); return; }
  blk -= 512;
  if (blk < 512) { packU2_one(Udec, Upk2D, blk * 256 + tid); return; }
  blk -= 512;
  if (blk < 4096) {
    int i = blk * 256 + tid, r = i >> 7;
    xembbf[i] = f2bf(emb[(size_t)x[r] * E_ + (i & 127)]);
    return;
  }
  blk -= 4096;
  {
    int i = blk * 256 + tid, r = i >> 7;
    dembbf[i] = f2bf(emb[(size_t)decx[r] * E_ + (i & 127)]);
  }
}

// ================= LSTM v12: lstm10 verbatim + honest occupancy attribute ==========
// ONLY change vs lstm10 (1182us best): amdgpu_waves_per_eu(4,4) tells the
// register allocator the truth -- LDS (148KB) caps us at 1 block/CU = 4
// waves/EU -- so the VGPR budget is 512/4 = 128, letting Ur[24] (96 dw)
// live in VGPRs instead of AGPRs (kills ~96 v_accvgpr_read/thread/step,
// ~29% of VALU issue).  Structure, layouts, barriers: identical to lstm10.
// Blocks >= 32 (decoder dispatch): Wgen transpose role.
#define DOT8(u0, u1, hpi)                \
  acc[0] = dot2u(u0.x, hpi, acc[0]);     \
  acc[1] = dot2u(u0.y, hpi, acc[1]);     \
  acc[2] = dot2u(u0.z, hpi, acc[2]);     \
  acc[3] = dot2u(u0.w, hpi, acc[3]);     \
  acc[4] = dot2u(u1.x, hpi, acc[4]);     \
  acc[5] = dot2u(u1.y, hpi, acc[5]);     \
  acc[6] = dot2u(u1.z, hpi, acc[6]);     \
  acc[7] = dot2u(u1.w, hpi, acc[7]);

__global__
__attribute__((amdgpu_flat_work_group_size(1024, 1024), amdgpu_waves_per_eu(4, 4)))
void lstm12(
    const float* __restrict__ Xpre, const unsigned* __restrict__ Upk2,
    const float* __restrict__ h0, const float* __restrict__ c0,
    ushort_t* __restrict__ outH, float* __restrict__ hN, float* __restrict__ cN,
    ushort_t* __restrict__ hNbf, ushort_t* __restrict__ cNbf,
    int steps, const float* __restrict__ Wg, ushort_t* __restrict__ WgT)
{
  __shared__ unsigned ldsU[8 * 4096];   // 131,072 B: [idx 0..7][tid]*4 dwords
  __shared__ float    zpart[4 * 1028];  //  16,448 B
  __shared__ unsigned hpair[8 * 20];    //     640 B
  const int tid = threadIdx.x;

  if (blockIdx.x >= 32) {
    // --- Wgen transpose role (runs on idle CUs during decoder) ---
    ushort_t* tile = (ushort_t*)ldsU;    // [64][65]
    int tb = blockIdx.x - 32;            // 3128 tiles: 4 k-tiles x 782 n-tiles
    int kb = (tb & 3) * 64, nb = (tb >> 2) * 64;
#pragma unroll
    for (int p = 0; p < 4; p++) {
      int i = p * 1024 + tid, k = i >> 6, n = i & 63;
      if (nb + n < V_) tile[k * 65 + n] = f2bf(Wg[(size_t)(kb + k) * V_ + nb + n]);
    }
    __syncthreads();
#pragma unroll
    for (int p = 0; p < 4; p++) {
      int i = p * 1024 + tid, n = i >> 6, k = i & 63;
      if (nb + n < V_) WgT[(size_t)(nb + n) * 256 + kb + k] = tile[k * 65 + n];
    }
    return;
  }

  const int b = blockIdx.x;
  const int jg = tid >> 3, kq = tid & 7;

  // load U: 12 pair-rows to regs, 4 to LDS (per-thread-contiguous layout)
  uint4 Ur[24];
  const unsigned* ubase = Upk2 + jg * 8;
#pragma unroll
  for (int i = 0; i < 12; i++) {
    int p = kq * 16 + i;
    Ur[2 * i]     = *(const uint4*)(ubase + p * 1024);
    Ur[2 * i + 1] = *(const uint4*)(ubase + p * 1024 + 4);
  }
  {
    unsigned* myst = &ldsU[tid * 4];
#pragma unroll
    for (int i = 0; i < 4; i++) {
      int p = kq * 16 + 12 + i;
      uint4 q0 = *(const uint4*)(ubase + p * 1024);
      uint4 q1 = *(const uint4*)(ubase + p * 1024 + 4);
      *(uint4*)(myst + (2 * i) * 4096)     = q0;
      *(uint4*)(myst + (2 * i + 1) * 4096) = q1;
    }
  }
  float c = 0.f, hcur = 0.f;
  if (tid < 256) {
    c    = c0 ? c0[b * 256 + tid] : 0.f;
    hcur = h0 ? h0[b * 256 + tid] : 0.f;
  }
  if (tid < 128) {
    float a  = h0 ? h0[b * 256 + 2 * tid] : 0.f;
    float b2 = h0 ? h0[b * 256 + 2 * tid + 1] : 0.f;
    U32H2 cv; cv.h = h2_t{(_Float16)a, (_Float16)b2};
    hpair[(tid >> 4) * 20 + (tid & 15)] = cv.u;   // pair P: addr (P>>4)*20 + (P&15)
  }
  __syncthreads();

  const float* xp = Xpre + (size_t)b * steps * 1024;
  const unsigned* myld = &ldsU[tid * 4];

  for (int t = 0; t < steps; t++) {
    // phase-2 prefetch: thread g's 4 gate x-preacts (consumed ~2000cy later)
    float xq0 = 0.f, xq1 = 0.f, xq2 = 0.f, xq3 = 0.f;
    if (tid < 256) {
      const float* xr = xp + (size_t)t * 1024 + tid;
      xq0 = xr[0]; xq1 = xr[256]; xq2 = xr[512]; xq3 = xr[768];
    }
    float acc[8] = {0.f, 0.f, 0.f, 0.f, 0.f, 0.f, 0.f, 0.f};
    {
      uint4 hA = *(const uint4*)&hpair[kq * 20];
      DOT8(Ur[0], Ur[1], hA.x)  DOT8(Ur[2], Ur[3], hA.y)
      DOT8(Ur[4], Ur[5], hA.z)  DOT8(Ur[6], Ur[7], hA.w)
    }
    {
      uint4 hB = *(const uint4*)&hpair[kq * 20 + 4];
      DOT8(Ur[8], Ur[9], hB.x)   DOT8(Ur[10], Ur[11], hB.y)
      DOT8(Ur[12], Ur[13], hB.z) DOT8(Ur[14], Ur[15], hB.w)
    }
    {
      uint4 hC = *(const uint4*)&hpair[kq * 20 + 8];
      DOT8(Ur[16], Ur[17], hC.x) DOT8(Ur[18], Ur[19], hC.y)
      DOT8(Ur[20], Ur[21], hC.z) DOT8(Ur[22], Ur[23], hC.w)
    }
    {
      uint4 hD = *(const uint4*)&hpair[kq * 20 + 12];
      unsigned hh[4] = {hD.x, hD.y, hD.z, hD.w};
#pragma unroll
      for (int r = 0; r < 4; r++) {
        uint4 u0 = *(const uint4*)(myld + (2 * r) * 4096);
        uint4 u1 = *(const uint4*)(myld + (2 * r + 1) * 4096);
        unsigned hpi = hh[r];
        DOT8(u0, u1, hpi)
      }
    }
#pragma unroll
    for (int g = 0; g < 8; g++) acc[g] += __shfl_xor(acc[g], 1);
    if ((kq & 1) == 0) {
      int r = kq >> 1;
      *(float4*)&zpart[r * 1028 + jg * 8]     = make_float4(acc[0], acc[1], acc[2], acc[3]);
      *(float4*)&zpart[r * 1028 + jg * 8 + 4] = make_float4(acc[4], acc[5], acc[6], acc[7]);
    }
    __syncthreads();   // A: zpart ready
    if (tid < 256) {
      float zi = xq0, zf = xq1, zg = xq2, zo = xq3;
#pragma unroll
      for (int r = 0; r < 4; r++) {
        const float* zr = &zpart[r * 1028 + tid];
        zi += zr[0]; zf += zr[256]; zg += zr[512]; zo += zr[768];
      }
      float ai = fast_sigm(zi), af = fast_sigm(zf);
      float ag = fast_tanh(zg), ao = fast_sigm(zo);
      c = fmaf(af, c, ai * ag);
      hcur = ao * fast_tanh(c);
      outH[((size_t)b * steps + t) * 256 + tid] = f2bf(hcur);
      float hnx = __shfl_down(hcur, 1);
      if ((tid & 1) == 0) {
        U32H2 cv; cv.h = h2_t{(_Float16)hcur, (_Float16)hnx};
        int P = tid >> 1;
        hpair[(P >> 4) * 20 + (P & 15)] = cv.u;
      }
    }
    __syncthreads();   // B: hpair(t+1) ready, zpart(t) consumed
  }
  if (tid < 256) {
    if (hN)   hN[b * 256 + tid] = hcur;
    if (cN)   cN[b * 256 + tid] = c;
    if (hNbf) hNbf[b * 256 + tid] = f2bf(hcur);
    if (cNbf) cNbf[b * 256 + tid] = f2bf(c);
  }
}

// ================= attention: one block per (b,t); writes bf16 catb directly ==========
__global__ __launch_bounds__(256) void attn_kernel(
    const float* __restrict__ dq, const ushort_t* __restrict__ enc,
    const int* __restrict__ x_len, const ushort_t* __restrict__ dec,
    ushort_t* __restrict__ catb)
{
  __shared__ float q[256];
  __shared__ float eb[32][256];
  __shared__ float sc[256];
  __shared__ float red[8];
  const int bt = blockIdx.x, tid = threadIdx.x;
  const int b = bt >> 4;
  q[tid] = dq[(size_t)bt * 256 + tid];
  const int len = x_len[b];
  const unsigned* encu = (const unsigned*)(enc + (size_t)b * S_ * 256);
  __syncthreads();
  const int s_loc = tid >> 3, hb = (tid & 7) * 32;
  for (int cch = 0; cch < 8; cch++) {
#pragma unroll
    for (int qv = 0; qv < 16; qv++) {
      int idx = qv * 256 + tid;
      unsigned u = encu[cch * 4096 + idx];
      int row = idx >> 7, cp2 = (idx & 127) * 2;
      eb[row][cp2]     = bf2f((unsigned short)(u & 0xffffu));
      eb[row][cp2 + 1] = bf2f((unsigned short)(u >> 16));
    }
    __syncthreads();
    float p = 0.f;
#pragma unroll
    for (int h = 0; h < 32; h++) p = fmaf(q[hb + h], eb[s_loc][hb + h], p);
    p += __shfl_down(p, 4, 8);
    p += __shfl_down(p, 2, 8);
    p += __shfl_down(p, 1, 8);
    if ((tid & 7) == 0) sc[cch * 32 + s_loc] = p;
    __syncthreads();
  }
  float my = (tid < len) ? sc[tid] : -1e30f;
  float m = my;
#pragma unroll
  for (int o = 32; o >= 1; o >>= 1) m = fmaxf(m, __shfl_xor(m, o));
  if ((tid & 63) == 0) red[tid >> 6] = m;
  __syncthreads();
  float bm = fmaxf(fmaxf(red[0], red[1]), fmaxf(red[2], red[3]));
  float e = expf(my - bm);
  float s = e;
#pragma unroll
  for (int o = 32; o >= 1; o >>= 1) s += __shfl_xor(s, o);
  if ((tid & 63) == 0) red[4 + (tid >> 6)] = s;
  __syncthreads();
  float tot = red[4] + red[5] + red[6] + red[7];
  sc[tid] = e / tot;
  __syncthreads();
  const ushort_t* encb = enc + (size_t)b * S_ * 256;
  float acc = 0.f;
  for (int s2 = 0; s2 < 256; s2++) acc = fmaf(sc[s2], bf2f(encb[(size_t)s2 * 256 + tid]), acc);
  catb[(size_t)bt * 512 + tid]       = f2bf(acc);                    // ctx half
  catb[(size_t)bt * 512 + 256 + tid] = dec[(size_t)bt * 256 + tid];  // dec half
}

// ================= copy scores: one block per (b,t); attn_out now bf16 ============
__global__ __launch_bounds__(256) void copyseq_kernel(
    const ushort_t* __restrict__ at, const ushort_t* __restrict__ cp,
    const int* __restrict__ x_len, float* __restrict__ cseq)
{
  __shared__ float q[256];
  __shared__ float eb[32][256];
  __shared__ float sc[256];
  const int bt = blockIdx.x, tid = threadIdx.x;
  const int b = bt >> 4;
  q[tid] = bf2f(at[(size_t)bt * 256 + tid]);
  const int len = x_len[b];
  const unsigned* cpu_ = (const unsigned*)(cp + (size_t)b * S_ * 256);
  __syncthreads();
  const int s_loc = tid >> 3, hb = (tid & 7) * 32;
  for (int cch = 0; cch < 8; cch++) {
#pragma unroll
    for (int qv = 0; qv < 16; qv++) {
      int idx = qv * 256 + tid;
      unsigned u = cpu_[cch * 4096 + idx];
      int row = idx >> 7, cp2 = (idx & 127) * 2;
      eb[row][cp2]     = bf2f((unsigned short)(u & 0xffffu));
      eb[row][cp2 + 1] = bf2f((unsigned short)(u >> 16));
    }
    __syncthreads();
    float p = 0.f;
#pragma unroll
    for (int h = 0; h < 32; h++) p = fmaf(q[hb + h], eb[s_loc][hb + h], p);
    p += __shfl_down(p, 4, 8);
    p += __shfl_down(p, 2, 8);
    p += __shfl_down(p, 1, 8);
    if ((tid & 7) == 0) sc[cch * 32 + s_loc] = p;
    __syncthreads();
  }
  cseq[(size_t)bt * 256 + tid] = (tid < len) ? expf(sc[tid]) : 0.f;
}

// ================= small kernels =================
// one block per bt-row; pads own row's OOV cells, then scatter-adds + row sum
__global__ __launch_bounds__(256) void scatter_kernel(
    const float* __restrict__ cseq, const int* __restrict__ xoov,
    float* __restrict__ out, float* __restrict__ rsum)
{
  __shared__ float red[4];
  const int bt = blockIdx.x, tid = threadIdx.x, b = bt >> 4;
  if (tid < OOV_) out[(size_t)bt * VO_ + V_ + tid] = 1e-10f;   // fused pad
  __syncthreads();
  float v = cseq[(size_t)bt * 256 + tid];
  if (v != 0.f) atomicAdd(&out[(size_t)bt * VO_ + xoov[b * S_ + tid]], v);
  float s = v;
#pragma unroll
  for (int o = 32; o >= 1; o >>= 1) s += __shfl_xor(s, o);
  if ((tid & 63) == 0) red[tid >> 6] = s;
  __syncthreads();
  if (tid == 0) atomicAdd(&rsum[bt], red[0] + red[1] + red[2] + red[3]);
}
__global__ void rowlog_kernel(const float* __restrict__ rsum, float* __restrict__ rowlog) {
  int i = blockIdx.x * 256 + threadIdx.x;
  if (i < B_ * T_) rowlog[i] = logf(rsum[i] + 1e-8f);  // +1e-8 = 100 pad cells * 1e-10
}
__global__ void finalize_kernel(float* __restrict__ out, const float* __restrict__ rowlog) {
  size_t i = (size_t)blockIdx.x * 256 + threadIdx.x;
  if (i < (size_t)B_ * T_ * VO_) {
    int bt = (int)(i / VO_);
    out[i] = logf(out[i]) - rowlog[bt];
  }
}

extern "C" void kernel_launch(void* const* d_in, const int* in_sizes, int n_in,
                              void* d_out, int out_size, void* d_ws, size_t ws_size,
                              hipStream_t stream) {
  const int*   x     = (const int*)d_in[0];
  const int*   xoov  = (const int*)d_in[1];
  const int*   xlen  = (const int*)d_in[2];
  const int*   decx  = (const int*)d_in[3];
  const float* emb   = (const float*)d_in[4];
  const float* Wenc  = (const float*)d_in[5];
  const float* Uenc  = (const float*)d_in[6];
  const float* benc  = (const float*)d_in[7];
  const float* We2d  = (const float*)d_in[8];
  const float* be2d  = (const float*)d_in[9];
  const float* Wdec  = (const float*)d_in[10];
  const float* Udec  = (const float*)d_in[11];
  const float* bdec  = (const float*)d_in[12];
  const float* Wattn = (const float*)d_in[13];
  const float* Wout  = (const float*)d_in[14];
  const float* bout  = (const float*)d_in[15];
  const float* Wgen  = (const float*)d_in[16];
  const float* Wcopy = (const float*)d_in[17];
  const float* bcopy = (const float*)d_in[18];
  float* out = (float*)d_out;
  float* ws  = (float*)d_ws;

  // ---- workspace layout (float offsets), ~47.6 MB ----
  float*    Xenc   = ws + 0;                         // 8,388,608 fl (dead after encoder)
  ushort_t* WgenT  = (ushort_t*)(ws + 0);            // phase2: 12.8M ush (decoder dispatch)
  ushort_t* cp_bf  = (ushort_t*)(ws + 6400000);      // phase2: 2.1M ush
  float*    dqb    = ws + 8388608;
  float*    cseq   = ws + 8781824;
  float*    rsum   = ws + 8912896;                   // 512
  float*    rowlog = ws + 8913408;                   // 512
  ushort_t* Abf    = (ushort_t*)(ws + 8913920);
  ushort_t* catb   = (ushort_t*)(ws + 8979456);
  ushort_t* decObf = (ushort_t*)(ws + 9110528);
  ushort_t* xembbf = (ushort_t*)(ws + 9176064);
  ushort_t* dembbf = (ushort_t*)(ws + 9700352);
  float*    Xdec   = ws + 9733120;
  ushort_t* WencT  = (ushort_t*)(ws + 10257408);
  ushort_t* WdecT  = (ushort_t*)(ws + 10322944);
  ushort_t* We2dT  = (ushort_t*)(ws + 10388480);
  ushort_t* WattnT = (ushort_t*)(ws + 10421248);
  ushort_t* WoutT  = (ushort_t*)(ws + 10454016);
  ushort_t* WcopyT = (ushort_t*)(ws + 10519552);
  unsigned* Upk2E  = (unsigned*)(ws + 10552320);
  unsigned* Upk2D  = (unsigned*)(ws + 10683392);
  ushort_t* encObf = (ushort_t*)(ws + 10814464);
  float*    ehc    = ws + 11863040;                  // unused f32 shadow (kept for safety)
  ushort_t* ehcbf  = (ushort_t*)(ws + 11879424);
  float*    h0c0   = ws + 11887616;

  float* sh  = out + (size_t)B_ * T_ * VO_;
  float* scf = sh + B_ * HD_;

  hipMemsetAsync(rsum, 0, 512 * sizeof(float), stream);

  hipLaunchKernelGGL(prep_kernel, dim3(5952), dim3(256), 0, stream,
                     Wenc, Wdec, We2d, Wattn, Wout, Wcopy, Uenc, Udec, x, decx, emb,
                     WencT, WdecT, We2dT, WattnT, WoutT, WcopyT, Upk2E, Upk2D,
                     xembbf, dembbf);

  hipLaunchKernelGGL(mfma_gemm, dim3(16, 128), dim3(256), 0, stream,
                     xembbf, WencT, benc, Xenc, (ushort_t*)nullptr, (float*)nullptr,
                     B_ * S_, 1024, 128, 1024, 0);
  hipLaunchKernelGGL(mfma_gemm, dim3(16, 8), dim3(256), 0, stream,
                     dembbf, WdecT, bdec, Xdec, (ushort_t*)nullptr, (float*)nullptr,
                     B_ * T_, 1024, 128, 1024, 0);

  // encoder: emits bf16 final states directly (ehcbf = [h | c])
  hipLaunchKernelGGL(lstm12, dim3(32), dim3(1024), 0, stream,
                     Xenc, Upk2E, (const float*)nullptr, (const float*)nullptr,
                     encObf, (float*)nullptr, (float*)nullptr,
                     ehcbf, ehcbf + 32 * 256, S_,
                     (const float*)nullptr, (ushort_t*)nullptr);

  hipLaunchKernelGGL(mfma_gemm, dim3(4, 1), dim3(256), 0, stream,
                     ehcbf, We2dT, be2d, h0c0, (ushort_t*)nullptr, (float*)nullptr,
                     64, 256, 256, 256, 0);

  // decoder + fused Wgen transpose on the idle 224 CUs (Xenc region is dead now)
  hipLaunchKernelGGL(lstm12, dim3(32 + 3128), dim3(1024), 0, stream,
                     Xdec, Upk2D, h0c0, h0c0 + 32 * 256, decObf, sh, scf,
                     (ushort_t*)nullptr, (ushort_t*)nullptr, T_,
                     Wgen, WgenT);

  hipLaunchKernelGGL(mfma_gemm, dim3(4, 8), dim3(256), 0, stream,
                     decObf, WattnT, (const float*)nullptr, dqb, (ushort_t*)nullptr,
                     (float*)nullptr, B_ * T_, 256, 256, 256, 0);
  hipLaunchKernelGGL(attn_kernel, dim3(B_ * T_), dim3(256), 0, stream,
                     dqb, encObf, xlen, decObf, catb);
  hipLaunchKernelGGL(mfma_gemm, dim3(4, 8), dim3(256), 0, stream,
                     catb, WoutT, bout, (float*)nullptr, Abf, (float*)nullptr,
                     B_ * T_, 256, 512, 256, 1);
  hipLaunchKernelGGL(mfma_gemm, dim3(4, 128), dim3(256), 0, stream,
                     encObf, WcopyT, bcopy, (float*)nullptr, cp_bf, (float*)nullptr,
                     B_ * S_, 256, 256, 256, 1);
  hipLaunchKernelGGL(mfma_gemm, dim3(782, 8), dim3(256), 0, stream,
                     Abf, WgenT, (const float*)nullptr, out, (ushort_t*)nullptr, rsum,
                     B_ * T_, V_, 256, VO_, 2);
  hipLaunchKernelGGL(copyseq_kernel, dim3(B_ * T_), dim3(256), 0, stream, Abf, cp_bf, xlen, cseq);
  hipLaunchKernelGGL(scatter_kernel, dim3(512), dim3(256), 0, stream, cseq, xoov, out, rsum);
  hipLaunchKernelGGL(rowlog_kernel, dim3(2), dim3(256), 0, stream, rsum, rowlog);
  hipLaunchKernelGGL(finalize_kernel, dim3((B_ * T_ * VO_ + 255) / 256), dim3(256), 0, stream,
                     out, rowlog);
}

// Round 9
// 1104.879 us; speedup vs baseline: 2.9376x; 1.0756x over previous
//
#include <hip/hip_runtime.h>

#define V_   50000
#define OOV_ 100
#define VO_  50100
#define E_   128
#define HE_  256
#define HD_  256
#define B_   32
#define S_   256
#define T_   16

typedef _Float16 h2_t __attribute__((ext_vector_type(2)));
typedef __attribute__((ext_vector_type(8))) short bfrag_t;
typedef __attribute__((ext_vector_type(4))) float f32x4;
typedef unsigned short ushort_t;

union U32H2 { unsigned u; h2_t h; };
union FRAG  { uint4 u; bfrag_t s; };

static __device__ __forceinline__ float bf2f(unsigned short b) {
  return __uint_as_float(((unsigned)b) << 16);
}
static __device__ __forceinline__ unsigned short f2bf(float f) {
  unsigned u = __float_as_uint(f);
  unsigned r = (u + 0x7fffu + ((u >> 16) & 1u)) >> 16;
  return (unsigned short)r;
}
static __device__ __forceinline__ float sigm(float x) { return 1.f / (1.f + expf(-x)); }
static __device__ __forceinline__ float fast_sigm(float z) {
  float e = __builtin_amdgcn_exp2f(-1.442695041f * z);
  return __builtin_amdgcn_rcpf(1.f + e);
}
static __device__ __forceinline__ float fast_tanh(float z) {
  float e = __builtin_amdgcn_exp2f(-2.885390082f * z);
  return 2.f * __builtin_amdgcn_rcpf(1.f + e) - 1.f;
}

static __device__ __forceinline__ float dot2u(unsigned upair, unsigned hpairv, float acc) {
  U32H2 a; a.u = upair;
  U32H2 b; b.u = hpairv;
#if __has_builtin(__builtin_amdgcn_fdot2)
  return __builtin_amdgcn_fdot2(a.h, b.h, acc, false);
#else
  acc = fmaf((float)a.h.x, (float)b.h.x, acc);
  return fmaf((float)a.h.y, (float)b.h.y, acc);
#endif
}

// ================= generic bf16 MFMA GEMM (+optional fused row-sum) =================
// C[M,ldC] = act(A[M,K]@Bt^T + bias); A row-major k-contig bf16; Bt [N][K] bf16.
// act: 0 none, 1 tanh, 2 exp. Cbf!=null -> bf16 out. rsum!=null -> atomicAdd row sums.
__global__ __launch_bounds__(256) void mfma_gemm(
    const ushort_t* __restrict__ A, const ushort_t* __restrict__ Bt,
    const float* __restrict__ bias, float* __restrict__ C, ushort_t* __restrict__ Cbf,
    float* __restrict__ rsum, int M, int N, int K, int ldC, int act)
{
  const int w = threadIdx.x >> 6, lane = threadIdx.x & 63;
  const int m0 = blockIdx.y * 64 + w * 16;
  const int n0 = blockIdx.x * 64;
  const int l16 = lane & 15, lq = lane >> 4;
  f32x4 acc[4] = {f32x4{0,0,0,0}, f32x4{0,0,0,0}, f32x4{0,0,0,0}, f32x4{0,0,0,0}};
  for (int k0 = 0; k0 < K; k0 += 32) {
    FRAG a;
    a.u = *(const uint4*)(A + (size_t)(m0 + l16) * K + k0 + lq * 8);
#pragma unroll
    for (int ns = 0; ns < 4; ns++) {
      int n = n0 + ns * 16 + l16;
      int nc = n < N ? n : N - 1;
      FRAG bf;
      bf.u = *(const uint4*)(Bt + (size_t)nc * K + k0 + lq * 8);
      acc[ns] = __builtin_amdgcn_mfma_f32_16x16x32_bf16(a.s, bf.s, acc[ns], 0, 0, 0);
    }
  }
  float bv[4];
#pragma unroll
  for (int ns = 0; ns < 4; ns++) {
    int col = n0 + ns * 16 + l16;
    bv[ns] = (bias && col < N) ? bias[col] : 0.f;
  }
#pragma unroll
  for (int r = 0; r < 4; r++) {
    int row = m0 + lq * 4 + r;   // C/D: col=lane&15, row=(lane>>4)*4+reg
    float part = 0.f;
#pragma unroll
    for (int ns = 0; ns < 4; ns++) {
      int col = n0 + ns * 16 + l16;
      if (col < N) {
        float v = acc[ns][r] + bv[ns];
        if (act == 1) v = tanhf(v);
        else if (act == 2) v = expf(v);
        if (Cbf) Cbf[(size_t)row * ldC + col] = f2bf(v);
        else     C[(size_t)row * ldC + col] = v;
        part += v;
      }
    }
    if (rsum) {
      part += __shfl_xor(part, 1);
      part += __shfl_xor(part, 2);
      part += __shfl_xor(part, 4);
      part += __shfl_xor(part, 8);
      if (l16 == 0) atomicAdd(&rsum[row], part);
    }
  }
}

// ================= Wgen GEMM: B staged from f32 Wgen (transpose-on-the-fly) ==========
// out[512][VO] = exp(Abf[512][256] @ Wgen[256][50000]); fused row-sum into rsum.
// One block per 64 vocab cols: stage B-tile (64 cols x K=256) from f32 Wgen into
// LDS (bf16, transposed, stride 264), then loop all 8 m-tiles of M=512.
// Wgen is read exactly once chip-wide (51.2MB); no WgenT buffer, no transpose pass.
__global__ __launch_bounds__(256) void wgen_gemm(
    const ushort_t* __restrict__ A, const float* __restrict__ Wg,
    float* __restrict__ out, float* __restrict__ rsum)
{
  __shared__ ushort_t ldsB[64 * 264];   // 33,792 B
  const int tid = threadIdx.x;
  const int n0 = blockIdx.x * 64;
  // stage: thread covers float4s of Wgen rows; write transposed bf16
#pragma unroll
  for (int it = 0; it < 16; it++) {
    int idx = it * 256 + tid;
    int k = idx >> 4, c4 = idx & 15;
    int nsrc = n0 + c4 * 4;
    if (nsrc > V_ - 4) nsrc = V_ - 4;      // clamp (dup values feed only unused cols)
    float4 f = *(const float4*)&Wg[(size_t)k * V_ + nsrc];
    ldsB[(c4 * 4 + 0) * 264 + k] = f2bf(f.x);
    ldsB[(c4 * 4 + 1) * 264 + k] = f2bf(f.y);
    ldsB[(c4 * 4 + 2) * 264 + k] = f2bf(f.z);
    ldsB[(c4 * 4 + 3) * 264 + k] = f2bf(f.w);
  }
  __syncthreads();
  const int w = tid >> 6, lane = tid & 63;
  const int l16 = lane & 15, lq = lane >> 4;
  for (int mt = 0; mt < 8; mt++) {
    const int mb = mt * 64 + w * 16;
    f32x4 acc[4] = {f32x4{0,0,0,0}, f32x4{0,0,0,0}, f32x4{0,0,0,0}, f32x4{0,0,0,0}};
#pragma unroll
    for (int k0 = 0; k0 < 256; k0 += 32) {
      FRAG a;
      a.u = *(const uint4*)(A + (size_t)(mb + l16) * 256 + k0 + lq * 8);
#pragma unroll
      for (int ns = 0; ns < 4; ns++) {
        FRAG bf;
        bf.u = *(const uint4*)&ldsB[(ns * 16 + l16) * 264 + k0 + lq * 8];
        acc[ns] = __builtin_amdgcn_mfma_f32_16x16x32_bf16(a.s, bf.s, acc[ns], 0, 0, 0);
      }
    }
#pragma unroll
    for (int r = 0; r < 4; r++) {
      int row = mb + lq * 4 + r;
      float part = 0.f;
#pragma unroll
      for (int ns = 0; ns < 4; ns++) {
        int col = n0 + ns * 16 + l16;
        if (col < V_) {
          float v = expf(acc[ns][r]);
          out[(size_t)row * VO_ + col] = v;
          part += v;
        }
      }
      part += __shfl_xor(part, 1);
      part += __shfl_xor(part, 2);
      part += __shfl_xor(part, 4);
      part += __shfl_xor(part, 8);
      if (l16 == 0) atomicAdd(&rsum[row], part);
    }
  }
}

// ================= prep: all weight transposes / packs / embeds, role-dispatched ==========
static __device__ __forceinline__ void tconv_tile(
    const float* __restrict__ W, ushort_t* __restrict__ Wt, int K, int N,
    int kb, int nb, int tid, ushort_t (*tile)[33])
{
  const int tx = tid & 31, ty = tid >> 5;
#pragma unroll
  for (int p = 0; p < 4; p++) {
    int k = kb + ty + p * 8, n = nb + tx;
    if (k < K && n < N) tile[ty + p * 8][tx] = f2bf(W[(size_t)k * N + n]);
  }
  __syncthreads();
#pragma unroll
  for (int p = 0; p < 4; p++) {
    int n = nb + ty + p * 8, k = kb + tx;
    if (k < K && n < N) Wt[(size_t)n * K + k] = tile[tx][ty + p * 8];
  }
}
static __device__ __forceinline__ void packU2_one(
    const float* __restrict__ U, unsigned* __restrict__ out, int i)
{
  int p = i >> 10, col = i & 1023;
  U32H2 cv; cv.h = h2_t{(_Float16)U[(size_t)(2 * p) * 1024 + col],
                        (_Float16)U[(size_t)(2 * p + 1) * 1024 + col]};
  out[i] = cv.u;
}

__global__ __launch_bounds__(256) void prep_kernel(
    const float* __restrict__ Wenc, const float* __restrict__ Wdec,
    const float* __restrict__ We2d, const float* __restrict__ Wattn,
    const float* __restrict__ Wout, const float* __restrict__ Wcopy,
    const float* __restrict__ Uenc, const float* __restrict__ Udec,
    const int* __restrict__ x, const int* __restrict__ decx, const float* __restrict__ emb,
    ushort_t* WencT, ushort_t* WdecT, ushort_t* We2dT, ushort_t* WattnT,
    ushort_t* WoutT, ushort_t* WcopyT, unsigned* Upk2E, unsigned* Upk2D,
    ushort_t* xembbf, ushort_t* dembbf)
{
  __shared__ ushort_t tile[32][33];
  int blk = blockIdx.x;
  const int tid = threadIdx.x;
  if (blk < 128) { tconv_tile(Wenc, WencT, 128, 1024, (blk >> 5) * 32, (blk & 31) * 32, tid, tile); return; }
  blk -= 128;
  if (blk < 128) { tconv_tile(Wdec, WdecT, 128, 1024, (blk >> 5) * 32, (blk & 31) * 32, tid, tile); return; }
  blk -= 128;
  if (blk < 64)  { tconv_tile(We2d, We2dT, 256, 256, (blk >> 3) * 32, (blk & 7) * 32, tid, tile); return; }
  blk -= 64;
  if (blk < 64)  { tconv_tile(Wattn, WattnT, 256, 256, (blk >> 3) * 32, (blk & 7) * 32, tid, tile); return; }
  blk -= 64;
  if (blk < 128) { tconv_tile(Wout, WoutT, 512, 256, (blk >> 3) * 32, (blk & 7) * 32, tid, tile); return; }
  blk -= 128;
  if (blk < 64)  { tconv_tile(Wcopy, WcopyT, 256, 256, (blk >> 3) * 32, (blk & 7) * 32, tid, tile); return; }
  blk -= 64;
  if (blk < 512) { packU2_one(Uenc, Upk2E, blk * 256 + tid); return; }
  blk -= 512;
  if (blk < 512) { packU2_one(Udec, Upk2D, blk * 256 + tid); return; }
  blk -= 512;
  if (blk < 4096) {
    int i = blk * 256 + tid, r = i >> 7;
    xembbf[i] = f2bf(emb[(size_t)x[r] * E_ + (i & 127)]);
    return;
  }
  blk -= 4096;
  {
    int i = blk * 256 + tid, r = i >> 7;
    dembbf[i] = f2bf(emb[(size_t)decx[r] * E_ + (i & 127)]);
  }
}

// ================= LSTM v12: lstm10 structure + honest occupancy attribute ==========
// (510us encoder floor; structure frozen.  Transpose role removed -- the Wgen
// transpose no longer exists anywhere.)
#define DOT8(u0, u1, hpi)                \
  acc[0] = dot2u(u0.x, hpi, acc[0]);     \
  acc[1] = dot2u(u0.y, hpi, acc[1]);     \
  acc[2] = dot2u(u0.z, hpi, acc[2]);     \
  acc[3] = dot2u(u0.w, hpi, acc[3]);     \
  acc[4] = dot2u(u1.x, hpi, acc[4]);     \
  acc[5] = dot2u(u1.y, hpi, acc[5]);     \
  acc[6] = dot2u(u1.z, hpi, acc[6]);     \
  acc[7] = dot2u(u1.w, hpi, acc[7]);

__global__
__attribute__((amdgpu_flat_work_group_size(1024, 1024), amdgpu_waves_per_eu(4, 4)))
void lstm12(
    const float* __restrict__ Xpre, const unsigned* __restrict__ Upk2,
    const float* __restrict__ h0, const float* __restrict__ c0,
    ushort_t* __restrict__ outH, float* __restrict__ hN, float* __restrict__ cN,
    ushort_t* __restrict__ hNbf, ushort_t* __restrict__ cNbf,
    int steps)
{
  __shared__ unsigned ldsU[8 * 4096];   // 131,072 B: [idx 0..7][tid]*4 dwords
  __shared__ float    zpart[4 * 1028];  //  16,448 B
  __shared__ unsigned hpair[8 * 20];    //     640 B
  const int tid = threadIdx.x;

  const int b = blockIdx.x;
  const int jg = tid >> 3, kq = tid & 7;

  // load U: 12 pair-rows to regs, 4 to LDS (per-thread-contiguous layout)
  uint4 Ur[24];
  const unsigned* ubase = Upk2 + jg * 8;
#pragma unroll
  for (int i = 0; i < 12; i++) {
    int p = kq * 16 + i;
    Ur[2 * i]     = *(const uint4*)(ubase + p * 1024);
    Ur[2 * i + 1] = *(const uint4*)(ubase + p * 1024 + 4);
  }
  {
    unsigned* myst = &ldsU[tid * 4];
#pragma unroll
    for (int i = 0; i < 4; i++) {
      int p = kq * 16 + 12 + i;
      uint4 q0 = *(const uint4*)(ubase + p * 1024);
      uint4 q1 = *(const uint4*)(ubase + p * 1024 + 4);
      *(uint4*)(myst + (2 * i) * 4096)     = q0;
      *(uint4*)(myst + (2 * i + 1) * 4096) = q1;
    }
  }
  float c = 0.f, hcur = 0.f;
  if (tid < 256) {
    c    = c0 ? c0[b * 256 + tid] : 0.f;
    hcur = h0 ? h0[b * 256 + tid] : 0.f;
  }
  if (tid < 128) {
    float a  = h0 ? h0[b * 256 + 2 * tid] : 0.f;
    float b2 = h0 ? h0[b * 256 + 2 * tid + 1] : 0.f;
    U32H2 cv; cv.h = h2_t{(_Float16)a, (_Float16)b2};
    hpair[(tid >> 4) * 20 + (tid & 15)] = cv.u;   // pair P: addr (P>>4)*20 + (P&15)
  }
  __syncthreads();

  const float* xp = Xpre + (size_t)b * steps * 1024;
  const unsigned* myld = &ldsU[tid * 4];

  for (int t = 0; t < steps; t++) {
    float xq0 = 0.f, xq1 = 0.f, xq2 = 0.f, xq3 = 0.f;
    if (tid < 256) {
      const float* xr = xp + (size_t)t * 1024 + tid;
      xq0 = xr[0]; xq1 = xr[256]; xq2 = xr[512]; xq3 = xr[768];
    }
    float acc[8] = {0.f, 0.f, 0.f, 0.f, 0.f, 0.f, 0.f, 0.f};
    {
      uint4 hA = *(const uint4*)&hpair[kq * 20];
      DOT8(Ur[0], Ur[1], hA.x)  DOT8(Ur[2], Ur[3], hA.y)
      DOT8(Ur[4], Ur[5], hA.z)  DOT8(Ur[6], Ur[7], hA.w)
    }
    {
      uint4 hB = *(const uint4*)&hpair[kq * 20 + 4];
      DOT8(Ur[8], Ur[9], hB.x)   DOT8(Ur[10], Ur[11], hB.y)
      DOT8(Ur[12], Ur[13], hB.z) DOT8(Ur[14], Ur[15], hB.w)
    }
    {
      uint4 hC = *(const uint4*)&hpair[kq * 20 + 8];
      DOT8(Ur[16], Ur[17], hC.x) DOT8(Ur[18], Ur[19], hC.y)
      DOT8(Ur[20], Ur[21], hC.z) DOT8(Ur[22], Ur[23], hC.w)
    }
    {
      uint4 hD = *(const uint4*)&hpair[kq * 20 + 12];
      unsigned hh[4] = {hD.x, hD.y, hD.z, hD.w};
#pragma unroll
      for (int r = 0; r < 4; r++) {
        uint4 u0 = *(const uint4*)(myld + (2 * r) * 4096);
        uint4 u1 = *(const uint4*)(myld + (2 * r + 1) * 4096);
        unsigned hpi = hh[r];
        DOT8(u0, u1, hpi)
      }
    }
#pragma unroll
    for (int g = 0; g < 8; g++) acc[g] += __shfl_xor(acc[g], 1);
    if ((kq & 1) == 0) {
      int r = kq >> 1;
      *(float4*)&zpart[r * 1028 + jg * 8]     = make_float4(acc[0], acc[1], acc[2], acc[3]);
      *(float4*)&zpart[r * 1028 + jg * 8 + 4] = make_float4(acc[4], acc[5], acc[6], acc[7]);
    }
    __syncthreads();   // A: zpart ready
    if (tid < 256) {
      float zi = xq0, zf = xq1, zg = xq2, zo = xq3;
#pragma unroll
      for (int r = 0; r < 4; r++) {
        const float* zr = &zpart[r * 1028 + tid];
        zi += zr[0]; zf += zr[256]; zg += zr[512]; zo += zr[768];
      }
      float ai = fast_sigm(zi), af = fast_sigm(zf);
      float ag = fast_tanh(zg), ao = fast_sigm(zo);
      c = fmaf(af, c, ai * ag);
      hcur = ao * fast_tanh(c);
      outH[((size_t)b * steps + t) * 256 + tid] = f2bf(hcur);
      float hnx = __shfl_down(hcur, 1);
      if ((tid & 1) == 0) {
        U32H2 cv; cv.h = h2_t{(_Float16)hcur, (_Float16)hnx};
        int P = tid >> 1;
        hpair[(P >> 4) * 20 + (P & 15)] = cv.u;
      }
    }
    __syncthreads();   // B: hpair(t+1) ready, zpart(t) consumed
  }
  if (tid < 256) {
    if (hN)   hN[b * 256 + tid] = hcur;
    if (cN)   cN[b * 256 + tid] = c;
    if (hNbf) hNbf[b * 256 + tid] = f2bf(hcur);
    if (cNbf) cNbf[b * 256 + tid] = f2bf(c);
  }
}

// ================= attention: one block per (b,t); writes bf16 catb directly ==========
__global__ __launch_bounds__(256) void attn_kernel(
    const float* __restrict__ dq, const ushort_t* __restrict__ enc,
    const int* __restrict__ x_len, const ushort_t* __restrict__ dec,
    ushort_t* __restrict__ catb)
{
  __shared__ float q[256];
  __shared__ float eb[32][256];
  __shared__ float sc[256];
  __shared__ float red[8];
  const int bt = blockIdx.x, tid = threadIdx.x;
  const int b = bt >> 4;
  q[tid] = dq[(size_t)bt * 256 + tid];
  const int len = x_len[b];
  const unsigned* encu = (const unsigned*)(enc + (size_t)b * S_ * 256);
  __syncthreads();
  const int s_loc = tid >> 3, hb = (tid & 7) * 32;
  for (int cch = 0; cch < 8; cch++) {
#pragma unroll
    for (int qv = 0; qv < 16; qv++) {
      int idx = qv * 256 + tid;
      unsigned u = encu[cch * 4096 + idx];
      int row = idx >> 7, cp2 = (idx & 127) * 2;
      eb[row][cp2]     = bf2f((unsigned short)(u & 0xffffu));
      eb[row][cp2 + 1] = bf2f((unsigned short)(u >> 16));
    }
    __syncthreads();
    float p = 0.f;
#pragma unroll
    for (int h = 0; h < 32; h++) p = fmaf(q[hb + h], eb[s_loc][hb + h], p);
    p += __shfl_down(p, 4, 8);
    p += __shfl_down(p, 2, 8);
    p += __shfl_down(p, 1, 8);
    if ((tid & 7) == 0) sc[cch * 32 + s_loc] = p;
    __syncthreads();
  }
  float my = (tid < len) ? sc[tid] : -1e30f;
  float m = my;
#pragma unroll
  for (int o = 32; o >= 1; o >>= 1) m = fmaxf(m, __shfl_xor(m, o));
  if ((tid & 63) == 0) red[tid >> 6] = m;
  __syncthreads();
  float bm = fmaxf(fmaxf(red[0], red[1]), fmaxf(red[2], red[3]));
  float e = expf(my - bm);
  float s = e;
#pragma unroll
  for (int o = 32; o >= 1; o >>= 1) s += __shfl_xor(s, o);
  if ((tid & 63) == 0) red[4 + (tid >> 6)] = s;
  __syncthreads();
  float tot = red[4] + red[5] + red[6] + red[7];
  sc[tid] = e / tot;
  __syncthreads();
  const ushort_t* encb = enc + (size_t)b * S_ * 256;
  float acc = 0.f;
  for (int s2 = 0; s2 < 256; s2++) acc = fmaf(sc[s2], bf2f(encb[(size_t)s2 * 256 + tid]), acc);
  catb[(size_t)bt * 512 + tid]       = f2bf(acc);                    // ctx half
  catb[(size_t)bt * 512 + 256 + tid] = dec[(size_t)bt * 256 + tid];  // dec half
}

// ================= copy scores: one block per (b,t); attn_out bf16 ============
__global__ __launch_bounds__(256) void copyseq_kernel(
    const ushort_t* __restrict__ at, const ushort_t* __restrict__ cp,
    const int* __restrict__ x_len, float* __restrict__ cseq)
{
  __shared__ float q[256];
  __shared__ float eb[32][256];
  __shared__ float sc[256];
  const int bt = blockIdx.x, tid = threadIdx.x;
  const int b = bt >> 4;
  q[tid] = bf2f(at[(size_t)bt * 256 + tid]);
  const int len = x_len[b];
  const unsigned* cpu_ = (const unsigned*)(cp + (size_t)b * S_ * 256);
  __syncthreads();
  const int s_loc = tid >> 3, hb = (tid & 7) * 32;
  for (int cch = 0; cch < 8; cch++) {
#pragma unroll
    for (int qv = 0; qv < 16; qv++) {
      int idx = qv * 256 + tid;
      unsigned u = cpu_[cch * 4096 + idx];
      int row = idx >> 7, cp2 = (idx & 127) * 2;
      eb[row][cp2]     = bf2f((unsigned short)(u & 0xffffu));
      eb[row][cp2 + 1] = bf2f((unsigned short)(u >> 16));
    }
    __syncthreads();
    float p = 0.f;
#pragma unroll
    for (int h = 0; h < 32; h++) p = fmaf(q[hb + h], eb[s_loc][hb + h], p);
    p += __shfl_down(p, 4, 8);
    p += __shfl_down(p, 2, 8);
    p += __shfl_down(p, 1, 8);
    if ((tid & 7) == 0) sc[cch * 32 + s_loc] = p;
    __syncthreads();
  }
  cseq[(size_t)bt * 256 + tid] = (tid < len) ? expf(sc[tid]) : 0.f;
}

// ================= small kernels =================
// one block per bt-row; pads own row's OOV cells, then scatter-adds + row sum
__global__ __launch_bounds__(256) void scatter_kernel(
    const float* __restrict__ cseq, const int* __restrict__ xoov,
    float* __restrict__ out, float* __restrict__ rsum)
{
  __shared__ float red[4];
  const int bt = blockIdx.x, tid = threadIdx.x, b = bt >> 4;
  if (tid < OOV_) out[(size_t)bt * VO_ + V_ + tid] = 1e-10f;   // fused pad
  __syncthreads();
  float v = cseq[(size_t)bt * 256 + tid];
  if (v != 0.f) atomicAdd(&out[(size_t)bt * VO_ + xoov[b * S_ + tid]], v);
  float s = v;
#pragma unroll
  for (int o = 32; o >= 1; o >>= 1) s += __shfl_xor(s, o);
  if ((tid & 63) == 0) red[tid >> 6] = s;
  __syncthreads();
  if (tid == 0) atomicAdd(&rsum[bt], red[0] + red[1] + red[2] + red[3]);
}
__global__ void rowlog_kernel(const float* __restrict__ rsum, float* __restrict__ rowlog) {
  int i = blockIdx.x * 256 + threadIdx.x;
  if (i < B_ * T_) rowlog[i] = logf(rsum[i] + 1e-8f);  // +1e-8 = 100 pad cells * 1e-10
}
__global__ void finalize_kernel(float* __restrict__ out, const float* __restrict__ rowlog) {
  size_t i = (size_t)blockIdx.x * 256 + threadIdx.x;
  if (i < (size_t)B_ * T_ * VO_) {
    int bt = (int)(i / VO_);
    out[i] = logf(out[i]) - rowlog[bt];
  }
}

extern "C" void kernel_launch(void* const* d_in, const int* in_sizes, int n_in,
                              void* d_out, int out_size, void* d_ws, size_t ws_size,
                              hipStream_t stream) {
  const int*   x     = (const int*)d_in[0];
  const int*   xoov  = (const int*)d_in[1];
  const int*   xlen  = (const int*)d_in[2];
  const int*   decx  = (const int*)d_in[3];
  const float* emb   = (const float*)d_in[4];
  const float* Wenc  = (const float*)d_in[5];
  const float* Uenc  = (const float*)d_in[6];
  const float* benc  = (const float*)d_in[7];
  const float* We2d  = (const float*)d_in[8];
  const float* be2d  = (const float*)d_in[9];
  const float* Wdec  = (const float*)d_in[10];
  const float* Udec  = (const float*)d_in[11];
  const float* bdec  = (const float*)d_in[12];
  const float* Wattn = (const float*)d_in[13];
  const float* Wout  = (const float*)d_in[14];
  const float* bout  = (const float*)d_in[15];
  const float* Wgen  = (const float*)d_in[16];
  const float* Wcopy = (const float*)d_in[17];
  const float* bcopy = (const float*)d_in[18];
  float* out = (float*)d_out;
  float* ws  = (float*)d_ws;

  // ---- workspace layout (float offsets) ----
  float*    Xenc   = ws + 0;                         // 8,388,608 fl (dead after encoder)
  ushort_t* cp_bf  = (ushort_t*)(ws + 6400000);      // phase2: 2.1M ush (Xenc dead then)
  float*    dqb    = ws + 8388608;
  float*    cseq   = ws + 8781824;
  float*    rsum   = ws + 8912896;                   // 512
  float*    rowlog = ws + 8913408;                   // 512
  ushort_t* Abf    = (ushort_t*)(ws + 8913920);
  ushort_t* catb   = (ushort_t*)(ws + 8979456);
  ushort_t* decObf = (ushort_t*)(ws + 9110528);
  ushort_t* xembbf = (ushort_t*)(ws + 9176064);
  ushort_t* dembbf = (ushort_t*)(ws + 9700352);
  float*    Xdec   = ws + 9733120;
  ushort_t* WencT  = (ushort_t*)(ws + 10257408);
  ushort_t* WdecT  = (ushort_t*)(ws + 10322944);
  ushort_t* We2dT  = (ushort_t*)(ws + 10388480);
  ushort_t* WattnT = (ushort_t*)(ws + 10421248);
  ushort_t* WoutT  = (ushort_t*)(ws + 10454016);
  ushort_t* WcopyT = (ushort_t*)(ws + 10519552);
  unsigned* Upk2E  = (unsigned*)(ws + 10552320);
  unsigned* Upk2D  = (unsigned*)(ws + 10683392);
  ushort_t* encObf = (ushort_t*)(ws + 10814464);
  ushort_t* ehcbf  = (ushort_t*)(ws + 11879424);
  float*    h0c0   = ws + 11887616;

  float* sh  = out + (size_t)B_ * T_ * VO_;
  float* scf = sh + B_ * HD_;

  hipMemsetAsync(rsum, 0, 512 * sizeof(float), stream);

  hipLaunchKernelGGL(prep_kernel, dim3(5952), dim3(256), 0, stream,
                     Wenc, Wdec, We2d, Wattn, Wout, Wcopy, Uenc, Udec, x, decx, emb,
                     WencT, WdecT, We2dT, WattnT, WoutT, WcopyT, Upk2E, Upk2D,
                     xembbf, dembbf);

  hipLaunchKernelGGL(mfma_gemm, dim3(16, 128), dim3(256), 0, stream,
                     xembbf, WencT, benc, Xenc, (ushort_t*)nullptr, (float*)nullptr,
                     B_ * S_, 1024, 128, 1024, 0);
  hipLaunchKernelGGL(mfma_gemm, dim3(16, 8), dim3(256), 0, stream,
                     dembbf, WdecT, bdec, Xdec, (ushort_t*)nullptr, (float*)nullptr,
                     B_ * T_, 1024, 128, 1024, 0);

  // encoder: emits bf16 final states directly (ehcbf = [h | c])
  hipLaunchKernelGGL(lstm12, dim3(32), dim3(1024), 0, stream,
                     Xenc, Upk2E, (const float*)nullptr, (const float*)nullptr,
                     encObf, (float*)nullptr, (float*)nullptr,
                     ehcbf, ehcbf + 32 * 256, S_);

  hipLaunchKernelGGL(mfma_gemm, dim3(4, 1), dim3(256), 0, stream,
                     ehcbf, We2dT, be2d, h0c0, (ushort_t*)nullptr, (float*)nullptr,
                     64, 256, 256, 256, 0);

  // decoder (32 blocks only -- Wgen transpose is gone entirely)
  hipLaunchKernelGGL(lstm12, dim3(32), dim3(1024), 0, stream,
                     Xdec, Upk2D, h0c0, h0c0 + 32 * 256, decObf, sh, scf,
                     (ushort_t*)nullptr, (ushort_t*)nullptr, T_);

  hipLaunchKernelGGL(mfma_gemm, dim3(4, 8), dim3(256), 0, stream,
                     decObf, WattnT, (const float*)nullptr, dqb, (ushort_t*)nullptr,
                     (float*)nullptr, B_ * T_, 256, 256, 256, 0);
  hipLaunchKernelGGL(attn_kernel, dim3(B_ * T_), dim3(256), 0, stream,
                     dqb, encObf, xlen, decObf, catb);
  hipLaunchKernelGGL(mfma_gemm, dim3(4, 8), dim3(256), 0, stream,
                     catb, WoutT, bout, (float*)nullptr, Abf, (float*)nullptr,
                     B_ * T_, 256, 512, 256, 1);
  hipLaunchKernelGGL(mfma_gemm, dim3(4, 128), dim3(256), 0, stream,
                     encObf, WcopyT, bcopy, (float*)nullptr, cp_bf, (float*)nullptr,
                     B_ * S_, 256, 256, 256, 1);
  // Wgen GEMM: reads f32 Wgen directly, transpose-on-the-fly into LDS
  hipLaunchKernelGGL(wgen_gemm, dim3(782), dim3(256), 0, stream,
                     Abf, Wgen, out, rsum);
  hipLaunchKernelGGL(copyseq_kernel, dim3(B_ * T_), dim3(256), 0, stream, Abf, cp_bf, xlen, cseq);
  hipLaunchKernelGGL(scatter_kernel, dim3(512), dim3(256), 0, stream, cseq, xoov, out, rsum);
  hipLaunchKernelGGL(rowlog_kernel, dim3(2), dim3(256), 0, stream, rsum, rowlog);
  hipLaunchKernelGGL(finalize_kernel, dim3((B_ * T_ * VO_ + 255) / 256), dim3(256), 0, stream,
                     out, rowlog);
}

// Round 10
// 1044.021 us; speedup vs baseline: 3.1089x; 1.0583x over previous
//
#include <hip/hip_runtime.h>

#define V_   50000
#define OOV_ 100
#define VO_  50100
#define E_   128
#define HE_  256
#define HD_  256
#define B_   32
#define S_   256
#define T_   16

typedef _Float16 h2_t __attribute__((ext_vector_type(2)));
typedef __attribute__((ext_vector_type(8))) short bfrag_t;
typedef __attribute__((ext_vector_type(4))) float f32x4;
typedef unsigned short ushort_t;

union U32H2 { unsigned u; h2_t h; };
union FRAG  { uint4 u; bfrag_t s; };

static __device__ __forceinline__ float bf2f(unsigned short b) {
  return __uint_as_float(((unsigned)b) << 16);
}
static __device__ __forceinline__ unsigned short f2bf(float f) {
  unsigned u = __float_as_uint(f);
  unsigned r = (u + 0x7fffu + ((u >> 16) & 1u)) >> 16;
  return (unsigned short)r;
}
static __device__ __forceinline__ float sigm(float x) { return 1.f / (1.f + expf(-x)); }
static __device__ __forceinline__ float fast_sigm(float z) {
  float e = __builtin_amdgcn_exp2f(-1.442695041f * z);
  return __builtin_amdgcn_rcpf(1.f + e);
}
static __device__ __forceinline__ float fast_tanh(float z) {
  float e = __builtin_amdgcn_exp2f(-2.885390082f * z);
  return 2.f * __builtin_amdgcn_rcpf(1.f + e) - 1.f;
}

static __device__ __forceinline__ float dot2u(unsigned upair, unsigned hpairv, float acc) {
  U32H2 a; a.u = upair;
  U32H2 b; b.u = hpairv;
#if __has_builtin(__builtin_amdgcn_fdot2)
  return __builtin_amdgcn_fdot2(a.h, b.h, acc, false);
#else
  acc = fmaf((float)a.h.x, (float)b.h.x, acc);
  return fmaf((float)a.h.y, (float)b.h.y, acc);
#endif
}

// ================= generic bf16 MFMA GEMM (+optional fused row-sum) =================
__global__ __launch_bounds__(256) void mfma_gemm(
    const ushort_t* __restrict__ A, const ushort_t* __restrict__ Bt,
    const float* __restrict__ bias, float* __restrict__ C, ushort_t* __restrict__ Cbf,
    float* __restrict__ rsum, int M, int N, int K, int ldC, int act)
{
  const int w = threadIdx.x >> 6, lane = threadIdx.x & 63;
  const int m0 = blockIdx.y * 64 + w * 16;
  const int n0 = blockIdx.x * 64;
  const int l16 = lane & 15, lq = lane >> 4;
  f32x4 acc[4] = {f32x4{0,0,0,0}, f32x4{0,0,0,0}, f32x4{0,0,0,0}, f32x4{0,0,0,0}};
  for (int k0 = 0; k0 < K; k0 += 32) {
    FRAG a;
    a.u = *(const uint4*)(A + (size_t)(m0 + l16) * K + k0 + lq * 8);
#pragma unroll
    for (int ns = 0; ns < 4; ns++) {
      int n = n0 + ns * 16 + l16;
      int nc = n < N ? n : N - 1;
      FRAG bf;
      bf.u = *(const uint4*)(Bt + (size_t)nc * K + k0 + lq * 8);
      acc[ns] = __builtin_amdgcn_mfma_f32_16x16x32_bf16(a.s, bf.s, acc[ns], 0, 0, 0);
    }
  }
  float bv[4];
#pragma unroll
  for (int ns = 0; ns < 4; ns++) {
    int col = n0 + ns * 16 + l16;
    bv[ns] = (bias && col < N) ? bias[col] : 0.f;
  }
#pragma unroll
  for (int r = 0; r < 4; r++) {
    int row = m0 + lq * 4 + r;   // C/D: col=lane&15, row=(lane>>4)*4+reg
    float part = 0.f;
#pragma unroll
    for (int ns = 0; ns < 4; ns++) {
      int col = n0 + ns * 16 + l16;
      if (col < N) {
        float v = acc[ns][r] + bv[ns];
        if (act == 1) v = tanhf(v);
        else if (act == 2) v = expf(v);
        if (Cbf) Cbf[(size_t)row * ldC + col] = f2bf(v);
        else     C[(size_t)row * ldC + col] = v;
        part += v;
      }
    }
    if (rsum) {
      part += __shfl_xor(part, 1);
      part += __shfl_xor(part, 2);
      part += __shfl_xor(part, 4);
      part += __shfl_xor(part, 8);
      if (l16 == 0) atomicAdd(&rsum[row], part);
    }
  }
}

// ================= Wgen GEMM: B staged from f32 Wgen (transpose-on-the-fly) ==========
__global__ __launch_bounds__(256) void wgen_gemm(
    const ushort_t* __restrict__ A, const float* __restrict__ Wg,
    float* __restrict__ out, float* __restrict__ rsum)
{
  __shared__ ushort_t ldsB[64 * 264];   // 33,792 B
  const int tid = threadIdx.x;
  const int n0 = blockIdx.x * 64;
#pragma unroll
  for (int it = 0; it < 16; it++) {
    int idx = it * 256 + tid;
    int k = idx >> 4, c4 = idx & 15;
    int nsrc = n0 + c4 * 4;
    if (nsrc > V_ - 4) nsrc = V_ - 4;      // clamp (dup values feed only unused cols)
    float4 f = *(const float4*)&Wg[(size_t)k * V_ + nsrc];
    ldsB[(c4 * 4 + 0) * 264 + k] = f2bf(f.x);
    ldsB[(c4 * 4 + 1) * 264 + k] = f2bf(f.y);
    ldsB[(c4 * 4 + 2) * 264 + k] = f2bf(f.z);
    ldsB[(c4 * 4 + 3) * 264 + k] = f2bf(f.w);
  }
  __syncthreads();
  const int w = tid >> 6, lane = tid & 63;
  const int l16 = lane & 15, lq = lane >> 4;
  for (int mt = 0; mt < 8; mt++) {
    const int mb = mt * 64 + w * 16;
    f32x4 acc[4] = {f32x4{0,0,0,0}, f32x4{0,0,0,0}, f32x4{0,0,0,0}, f32x4{0,0,0,0}};
#pragma unroll
    for (int k0 = 0; k0 < 256; k0 += 32) {
      FRAG a;
      a.u = *(const uint4*)(A + (size_t)(mb + l16) * 256 + k0 + lq * 8);
#pragma unroll
      for (int ns = 0; ns < 4; ns++) {
        FRAG bf;
        bf.u = *(const uint4*)&ldsB[(ns * 16 + l16) * 264 + k0 + lq * 8];
        acc[ns] = __builtin_amdgcn_mfma_f32_16x16x32_bf16(a.s, bf.s, acc[ns], 0, 0, 0);
      }
    }
#pragma unroll
    for (int r = 0; r < 4; r++) {
      int row = mb + lq * 4 + r;
      float part = 0.f;
#pragma unroll
      for (int ns = 0; ns < 4; ns++) {
        int col = n0 + ns * 16 + l16;
        if (col < V_) {
          float v = expf(acc[ns][r]);
          out[(size_t)row * VO_ + col] = v;
          part += v;
        }
      }
      part += __shfl_xor(part, 1);
      part += __shfl_xor(part, 2);
      part += __shfl_xor(part, 4);
      part += __shfl_xor(part, 8);
      if (l16 == 0) atomicAdd(&rsum[row], part);
    }
  }
}

// ================= prep: all weight transposes / packs / embeds, role-dispatched ==========
static __device__ __forceinline__ void tconv_tile(
    const float* __restrict__ W, ushort_t* __restrict__ Wt, int K, int N,
    int kb, int nb, int tid, ushort_t (*tile)[33])
{
  const int tx = tid & 31, ty = tid >> 5;
#pragma unroll
  for (int p = 0; p < 4; p++) {
    int k = kb + ty + p * 8, n = nb + tx;
    if (k < K && n < N) tile[ty + p * 8][tx] = f2bf(W[(size_t)k * N + n]);
  }
  __syncthreads();
#pragma unroll
  for (int p = 0; p < 4; p++) {
    int n = nb + ty + p * 8, k = kb + tx;
    if (k < K && n < N) Wt[(size_t)n * K + k] = tile[tx][ty + p * 8];
  }
}
static __device__ __forceinline__ void packU2_one(
    const float* __restrict__ U, unsigned* __restrict__ out, int i)
{
  int p = i >> 10, col = i & 1023;
  U32H2 cv; cv.h = h2_t{(_Float16)U[(size_t)(2 * p) * 1024 + col],
                        (_Float16)U[(size_t)(2 * p + 1) * 1024 + col]};
  out[i] = cv.u;
}

__global__ __launch_bounds__(256) void prep_kernel(
    const float* __restrict__ Wenc, const float* __restrict__ Wdec,
    const float* __restrict__ We2d, const float* __restrict__ Wattn,
    const float* __restrict__ Wout, const float* __restrict__ Wcopy,
    const float* __restrict__ Uenc, const float* __restrict__ Udec,
    const int* __restrict__ x, const int* __restrict__ decx, const float* __restrict__ emb,
    ushort_t* WencT, ushort_t* WdecT, ushort_t* We2dT, ushort_t* WattnT,
    ushort_t* WoutT, ushort_t* WcopyT, unsigned* Upk2E, unsigned* Upk2D,
    ushort_t* xembbf, ushort_t* dembbf)
{
  __shared__ ushort_t tile[32][33];
  int blk = blockIdx.x;
  const int tid = threadIdx.x;
  if (blk < 128) { tconv_tile(Wenc, WencT, 128, 1024, (blk >> 5) * 32, (blk & 31) * 32, tid, tile); return; }
  blk -= 128;
  if (blk < 128) { tconv_tile(Wdec, WdecT, 128, 1024, (blk >> 5) * 32, (blk & 31) * 32, tid, tile); return; }
  blk -= 128;
  if (blk < 64)  { tconv_tile(We2d, We2dT, 256, 256, (blk >> 3) * 32, (blk & 7) * 32, tid, tile); return; }
  blk -= 64;
  if (blk < 64)  { tconv_tile(Wattn, WattnT, 256, 256, (blk >> 3) * 32, (blk & 7) * 32, tid, tile); return; }
  blk -= 64;
  if (blk < 128) { tconv_tile(Wout, WoutT, 512, 256, (blk >> 3) * 32, (blk & 7) * 32, tid, tile); return; }
  blk -= 128;
  if (blk < 64)  { tconv_tile(Wcopy, WcopyT, 256, 256, (blk >> 3) * 32, (blk & 7) * 32, tid, tile); return; }
  blk -= 64;
  if (blk < 512) { packU2_one(Uenc, Upk2E, blk * 256 + tid); return; }
  blk -= 512;
  if (blk < 512) { packU2_one(Udec, Upk2D, blk * 256 + tid); return; }
  blk -= 512;
  if (blk < 4096) {
    int i = blk * 256 + tid, r = i >> 7;
    xembbf[i] = f2bf(emb[(size_t)x[r] * E_ + (i & 127)]);
    return;
  }
  blk -= 4096;
  {
    int i = blk * 256 + tid, r = i >> 7;
    dembbf[i] = f2bf(emb[(size_t)decx[r] * E_ + (i & 127)]);
  }
}

// ================= LSTM v12 + fused Wcopy-GEMM role (decoder dispatch) ==========
// Blocks < 32: lstm recurrence (510us-floor structure, frozen).
// Blocks >= 32 (decoder dispatch only): Wcopy GEMM role -- cp_bf = tanh(encObf @
// WcopyT^T + bcopy).  Depends only on encObf (ready pre-decoder), runs on the
// 224 idle CUs during the decoder's ~50us -> fully hidden.
#define DOT8(u0, u1, hpi)                \
  acc[0] = dot2u(u0.x, hpi, acc[0]);     \
  acc[1] = dot2u(u0.y, hpi, acc[1]);     \
  acc[2] = dot2u(u0.z, hpi, acc[2]);     \
  acc[3] = dot2u(u0.w, hpi, acc[3]);     \
  acc[4] = dot2u(u1.x, hpi, acc[4]);     \
  acc[5] = dot2u(u1.y, hpi, acc[5]);     \
  acc[6] = dot2u(u1.z, hpi, acc[6]);     \
  acc[7] = dot2u(u1.w, hpi, acc[7]);

__global__
__attribute__((amdgpu_flat_work_group_size(1024, 1024), amdgpu_waves_per_eu(4, 4)))
void lstm12(
    const float* __restrict__ Xpre, const unsigned* __restrict__ Upk2,
    const float* __restrict__ h0, const float* __restrict__ c0,
    ushort_t* __restrict__ outH, float* __restrict__ hN, float* __restrict__ cN,
    ushort_t* __restrict__ hNbf, ushort_t* __restrict__ cNbf,
    int steps,
    const ushort_t* __restrict__ encA, const ushort_t* __restrict__ WcT,
    const float* __restrict__ bcp, ushort_t* __restrict__ cpout)
{
  __shared__ unsigned ldsU[8 * 4096];   // 131,072 B: [idx 0..7][tid]*4 dwords
  __shared__ float    zpart[4 * 1028];  //  16,448 B
  __shared__ unsigned hpair[8 * 20];    //     640 B
  const int tid = threadIdx.x;

  if (blockIdx.x >= 32) {
    // --- Wcopy GEMM role: 128 blocks, each 256 rows x 64 cols ---
    int tb = blockIdx.x - 32;            // (n-tile 0..3) x (m-tile 0..31)
    const int n0 = (tb & 3) * 64;
    const int mt = tb >> 2;
    const int w = tid >> 6, lane = tid & 63;
    const int l16 = lane & 15, lq = lane >> 4;
    const int m0 = mt * 256 + w * 16;
    f32x4 acc[4] = {f32x4{0,0,0,0}, f32x4{0,0,0,0}, f32x4{0,0,0,0}, f32x4{0,0,0,0}};
#pragma unroll
    for (int k0 = 0; k0 < 256; k0 += 32) {
      FRAG a;
      a.u = *(const uint4*)(encA + (size_t)(m0 + l16) * 256 + k0 + lq * 8);
#pragma unroll
      for (int ns = 0; ns < 4; ns++) {
        FRAG bf;
        bf.u = *(const uint4*)(WcT + (size_t)(n0 + ns * 16 + l16) * 256 + k0 + lq * 8);
        acc[ns] = __builtin_amdgcn_mfma_f32_16x16x32_bf16(a.s, bf.s, acc[ns], 0, 0, 0);
      }
    }
#pragma unroll
    for (int r = 0; r < 4; r++) {
      int row = m0 + lq * 4 + r;
#pragma unroll
      for (int ns = 0; ns < 4; ns++) {
        int col = n0 + ns * 16 + l16;
        cpout[(size_t)row * 256 + col] = f2bf(tanhf(acc[ns][r] + bcp[col]));
      }
    }
    return;
  }

  const int b = blockIdx.x;
  const int jg = tid >> 3, kq = tid & 7;

  // load U: 12 pair-rows to regs, 4 to LDS (per-thread-contiguous layout)
  uint4 Ur[24];
  const unsigned* ubase = Upk2 + jg * 8;
#pragma unroll
  for (int i = 0; i < 12; i++) {
    int p = kq * 16 + i;
    Ur[2 * i]     = *(const uint4*)(ubase + p * 1024);
    Ur[2 * i + 1] = *(const uint4*)(ubase + p * 1024 + 4);
  }
  {
    unsigned* myst = &ldsU[tid * 4];
#pragma unroll
    for (int i = 0; i < 4; i++) {
      int p = kq * 16 + 12 + i;
      uint4 q0 = *(const uint4*)(ubase + p * 1024);
      uint4 q1 = *(const uint4*)(ubase + p * 1024 + 4);
      *(uint4*)(myst + (2 * i) * 4096)     = q0;
      *(uint4*)(myst + (2 * i + 1) * 4096) = q1;
    }
  }
  float c = 0.f, hcur = 0.f;
  if (tid < 256) {
    c    = c0 ? c0[b * 256 + tid] : 0.f;
    hcur = h0 ? h0[b * 256 + tid] : 0.f;
  }
  if (tid < 128) {
    float a  = h0 ? h0[b * 256 + 2 * tid] : 0.f;
    float b2 = h0 ? h0[b * 256 + 2 * tid + 1] : 0.f;
    U32H2 cv; cv.h = h2_t{(_Float16)a, (_Float16)b2};
    hpair[(tid >> 4) * 20 + (tid & 15)] = cv.u;   // pair P: addr (P>>4)*20 + (P&15)
  }
  __syncthreads();

  const float* xp = Xpre + (size_t)b * steps * 1024;
  const unsigned* myld = &ldsU[tid * 4];

  for (int t = 0; t < steps; t++) {
    float xq0 = 0.f, xq1 = 0.f, xq2 = 0.f, xq3 = 0.f;
    if (tid < 256) {
      const float* xr = xp + (size_t)t * 1024 + tid;
      xq0 = xr[0]; xq1 = xr[256]; xq2 = xr[512]; xq3 = xr[768];
    }
    float acc[8] = {0.f, 0.f, 0.f, 0.f, 0.f, 0.f, 0.f, 0.f};
    {
      uint4 hA = *(const uint4*)&hpair[kq * 20];
      DOT8(Ur[0], Ur[1], hA.x)  DOT8(Ur[2], Ur[3], hA.y)
      DOT8(Ur[4], Ur[5], hA.z)  DOT8(Ur[6], Ur[7], hA.w)
    }
    {
      uint4 hB = *(const uint4*)&hpair[kq * 20 + 4];
      DOT8(Ur[8], Ur[9], hB.x)   DOT8(Ur[10], Ur[11], hB.y)
      DOT8(Ur[12], Ur[13], hB.z) DOT8(Ur[14], Ur[15], hB.w)
    }
    {
      uint4 hC = *(const uint4*)&hpair[kq * 20 + 8];
      DOT8(Ur[16], Ur[17], hC.x) DOT8(Ur[18], Ur[19], hC.y)
      DOT8(Ur[20], Ur[21], hC.z) DOT8(Ur[22], Ur[23], hC.w)
    }
    {
      uint4 hD = *(const uint4*)&hpair[kq * 20 + 12];
      unsigned hh[4] = {hD.x, hD.y, hD.z, hD.w};
#pragma unroll
      for (int r = 0; r < 4; r++) {
        uint4 u0 = *(const uint4*)(myld + (2 * r) * 4096);
        uint4 u1 = *(const uint4*)(myld + (2 * r + 1) * 4096);
        unsigned hpi = hh[r];
        DOT8(u0, u1, hpi)
      }
    }
#pragma unroll
    for (int g = 0; g < 8; g++) acc[g] += __shfl_xor(acc[g], 1);
    if ((kq & 1) == 0) {
      int r = kq >> 1;
      *(float4*)&zpart[r * 1028 + jg * 8]     = make_float4(acc[0], acc[1], acc[2], acc[3]);
      *(float4*)&zpart[r * 1028 + jg * 8 + 4] = make_float4(acc[4], acc[5], acc[6], acc[7]);
    }
    __syncthreads();   // A: zpart ready
    if (tid < 256) {
      float zi = xq0, zf = xq1, zg = xq2, zo = xq3;
#pragma unroll
      for (int r = 0; r < 4; r++) {
        const float* zr = &zpart[r * 1028 + tid];
        zi += zr[0]; zf += zr[256]; zg += zr[512]; zo += zr[768];
      }
      float ai = fast_sigm(zi), af = fast_sigm(zf);
      float ag = fast_tanh(zg), ao = fast_sigm(zo);
      c = fmaf(af, c, ai * ag);
      hcur = ao * fast_tanh(c);
      outH[((size_t)b * steps + t) * 256 + tid] = f2bf(hcur);
      float hnx = __shfl_down(hcur, 1);
      if ((tid & 1) == 0) {
        U32H2 cv; cv.h = h2_t{(_Float16)hcur, (_Float16)hnx};
        int P = tid >> 1;
        hpair[(P >> 4) * 20 + (P & 15)] = cv.u;
      }
    }
    __syncthreads();   // B: hpair(t+1) ready, zpart(t) consumed
  }
  if (tid < 256) {
    if (hN)   hN[b * 256 + tid] = hcur;
    if (cN)   cN[b * 256 + tid] = c;
    if (hNbf) hNbf[b * 256 + tid] = f2bf(hcur);
    if (cNbf) cNbf[b * 256 + tid] = f2bf(c);
  }
}

// ================= attention: fused q = dec@Wattn; len-skip; writes bf16 catb ==========
__global__ __launch_bounds__(256) void attn_kernel(
    const ushort_t* __restrict__ dec, const ushort_t* __restrict__ WattnT,
    const ushort_t* __restrict__ enc, const int* __restrict__ x_len,
    ushort_t* __restrict__ catb)
{
  __shared__ float q[256];
  __shared__ float decf[256];
  __shared__ float eb[32][256];
  __shared__ float sc[256];
  __shared__ float red[8];
  const int bt = blockIdx.x, tid = threadIdx.x;
  const int b = bt >> 4;
  const int len = x_len[b];
  // stage dec row as f32
  if (tid < 128) {
    unsigned u = ((const unsigned*)(dec + (size_t)bt * 256))[tid];
    decf[2 * tid]     = bf2f((unsigned short)(u & 0xffffu));
    decf[2 * tid + 1] = bf2f((unsigned short)(u >> 16));
  }
  __syncthreads();
  // q[tid] = sum_k decf[k] * WattnT[tid][k]   (inline Wattn GEMV)
  {
    const ushort_t* wrow = WattnT + (size_t)tid * 256;
    float acc = 0.f;
#pragma unroll 4
    for (int k0 = 0; k0 < 256; k0 += 8) {
      uint4 wv = *(const uint4*)(wrow + k0);
      unsigned ws[4] = {wv.x, wv.y, wv.z, wv.w};
#pragma unroll
      for (int e = 0; e < 4; e++) {
        acc = fmaf(decf[k0 + 2 * e],     bf2f((unsigned short)(ws[e] & 0xffffu)), acc);
        acc = fmaf(decf[k0 + 2 * e + 1], bf2f((unsigned short)(ws[e] >> 16)),     acc);
      }
    }
    q[tid] = acc;
  }
  __syncthreads();
  const unsigned* encu = (const unsigned*)(enc + (size_t)b * S_ * 256);
  const int s_loc = tid >> 3, hb = (tid & 7) * 32;
  const int nch = (len + 31) >> 5;   // only score chunks with s < len
  for (int cch = 0; cch < nch; cch++) {
#pragma unroll
    for (int qv = 0; qv < 16; qv++) {
      int idx = qv * 256 + tid;
      unsigned u = encu[cch * 4096 + idx];
      int row = idx >> 7, cp2 = (idx & 127) * 2;
      eb[row][cp2]     = bf2f((unsigned short)(u & 0xffffu));
      eb[row][cp2 + 1] = bf2f((unsigned short)(u >> 16));
    }
    __syncthreads();
    float p = 0.f;
#pragma unroll
    for (int h = 0; h < 32; h++) p = fmaf(q[hb + h], eb[s_loc][hb + h], p);
    p += __shfl_down(p, 4, 8);
    p += __shfl_down(p, 2, 8);
    p += __shfl_down(p, 1, 8);
    if ((tid & 7) == 0) sc[cch * 32 + s_loc] = p;
    __syncthreads();
  }
  float my = (tid < len) ? sc[tid] : -1e30f;
  float m = my;
#pragma unroll
  for (int o = 32; o >= 1; o >>= 1) m = fmaxf(m, __shfl_xor(m, o));
  if ((tid & 63) == 0) red[tid >> 6] = m;
  __syncthreads();
  float bm = fmaxf(fmaxf(red[0], red[1]), fmaxf(red[2], red[3]));
  float e = expf(my - bm);
  float s = e;
#pragma unroll
  for (int o = 32; o >= 1; o >>= 1) s += __shfl_xor(s, o);
  if ((tid & 63) == 0) red[4 + (tid >> 6)] = s;
  __syncthreads();
  float tot = red[4] + red[5] + red[6] + red[7];
  sc[tid] = e / tot;
  __syncthreads();
  const ushort_t* encb = enc + (size_t)b * S_ * 256;
  float acc = 0.f;
  for (int s2 = 0; s2 < len; s2++) acc = fmaf(sc[s2], bf2f(encb[(size_t)s2 * 256 + tid]), acc);
  catb[(size_t)bt * 512 + tid]       = f2bf(acc);                    // ctx half
  catb[(size_t)bt * 512 + 256 + tid] = dec[(size_t)bt * 256 + tid];  // dec half
}

// ================= copy scores: len-skip; attn_out bf16 ============
__global__ __launch_bounds__(256) void copyseq_kernel(
    const ushort_t* __restrict__ at, const ushort_t* __restrict__ cp,
    const int* __restrict__ x_len, float* __restrict__ cseq)
{
  __shared__ float q[256];
  __shared__ float eb[32][256];
  __shared__ float sc[256];
  const int bt = blockIdx.x, tid = threadIdx.x;
  const int b = bt >> 4;
  q[tid] = bf2f(at[(size_t)bt * 256 + tid]);
  const int len = x_len[b];
  const unsigned* cpu_ = (const unsigned*)(cp + (size_t)b * S_ * 256);
  __syncthreads();
  const int s_loc = tid >> 3, hb = (tid & 7) * 32;
  const int nch = (len + 31) >> 5;
  for (int cch = 0; cch < nch; cch++) {
#pragma unroll
    for (int qv = 0; qv < 16; qv++) {
      int idx = qv * 256 + tid;
      unsigned u = cpu_[cch * 4096 + idx];
      int row = idx >> 7, cp2 = (idx & 127) * 2;
      eb[row][cp2]     = bf2f((unsigned short)(u & 0xffffu));
      eb[row][cp2 + 1] = bf2f((unsigned short)(u >> 16));
    }
    __syncthreads();
    float p = 0.f;
#pragma unroll
    for (int h = 0; h < 32; h++) p = fmaf(q[hb + h], eb[s_loc][hb + h], p);
    p += __shfl_down(p, 4, 8);
    p += __shfl_down(p, 2, 8);
    p += __shfl_down(p, 1, 8);
    if ((tid & 7) == 0) sc[cch * 32 + s_loc] = p;
    __syncthreads();
  }
  cseq[(size_t)bt * 256 + tid] = (tid < len) ? expf(sc[tid]) : 0.f;
}

// ================= small kernels =================
__global__ __launch_bounds__(256) void scatter_kernel(
    const float* __restrict__ cseq, const int* __restrict__ xoov,
    float* __restrict__ out, float* __restrict__ rsum)
{
  __shared__ float red[4];
  const int bt = blockIdx.x, tid = threadIdx.x, b = bt >> 4;
  if (tid < OOV_) out[(size_t)bt * VO_ + V_ + tid] = 1e-10f;   // fused pad
  __syncthreads();
  float v = cseq[(size_t)bt * 256 + tid];
  if (v != 0.f) atomicAdd(&out[(size_t)bt * VO_ + xoov[b * S_ + tid]], v);
  float s = v;
#pragma unroll
  for (int o = 32; o >= 1; o >>= 1) s += __shfl_xor(s, o);
  if ((tid & 63) == 0) red[tid >> 6] = s;
  __syncthreads();
  if (tid == 0) atomicAdd(&rsum[bt], red[0] + red[1] + red[2] + red[3]);
}
__global__ void rowlog_kernel(const float* __restrict__ rsum, float* __restrict__ rowlog) {
  int i = blockIdx.x * 256 + threadIdx.x;
  if (i < B_ * T_) rowlog[i] = logf(rsum[i] + 1e-8f);  // +1e-8 = 100 pad cells * 1e-10
}
// float4-vectorized: VO_=50100 is divisible by 4, rows 16B-aligned
__global__ void finalize_kernel(float* __restrict__ out, const float* __restrict__ rowlog) {
  size_t i4 = ((size_t)blockIdx.x * 256 + threadIdx.x) * 4;
  if (i4 < (size_t)B_ * T_ * VO_) {
    int bt = (int)(i4 / VO_);
    float rl = rowlog[bt];
    float4 v = *(float4*)&out[i4];
    v.x = logf(v.x) - rl;
    v.y = logf(v.y) - rl;
    v.z = logf(v.z) - rl;
    v.w = logf(v.w) - rl;
    *(float4*)&out[i4] = v;
  }
}

extern "C" void kernel_launch(void* const* d_in, const int* in_sizes, int n_in,
                              void* d_out, int out_size, void* d_ws, size_t ws_size,
                              hipStream_t stream) {
  const int*   x     = (const int*)d_in[0];
  const int*   xoov  = (const int*)d_in[1];
  const int*   xlen  = (const int*)d_in[2];
  const int*   decx  = (const int*)d_in[3];
  const float* emb   = (const float*)d_in[4];
  const float* Wenc  = (const float*)d_in[5];
  const float* Uenc  = (const float*)d_in[6];
  const float* benc  = (const float*)d_in[7];
  const float* We2d  = (const float*)d_in[8];
  const float* be2d  = (const float*)d_in[9];
  const float* Wdec  = (const float*)d_in[10];
  const float* Udec  = (const float*)d_in[11];
  const float* bdec  = (const float*)d_in[12];
  const float* Wattn = (const float*)d_in[13];
  const float* Wout  = (const float*)d_in[14];
  const float* bout  = (const float*)d_in[15];
  const float* Wgen  = (const float*)d_in[16];
  const float* Wcopy = (const float*)d_in[17];
  const float* bcopy = (const float*)d_in[18];
  float* out = (float*)d_out;
  float* ws  = (float*)d_ws;

  // ---- workspace layout (float offsets) ----
  float*    Xenc   = ws + 0;                         // 8,388,608 fl (dead after encoder)
  ushort_t* cp_bf  = (ushort_t*)(ws + 6400000);      // phase2: 2.1M ush (Xenc dead then)
  float*    cseq   = ws + 8781824;
  float*    rsum   = ws + 8912896;                   // 512
  float*    rowlog = ws + 8913408;                   // 512
  ushort_t* Abf    = (ushort_t*)(ws + 8913920);
  ushort_t* catb   = (ushort_t*)(ws + 8979456);
  ushort_t* decObf = (ushort_t*)(ws + 9110528);
  ushort_t* xembbf = (ushort_t*)(ws + 9176064);
  ushort_t* dembbf = (ushort_t*)(ws + 9700352);
  float*    Xdec   = ws + 9733120;
  ushort_t* WencT  = (ushort_t*)(ws + 10257408);
  ushort_t* WdecT  = (ushort_t*)(ws + 10322944);
  ushort_t* We2dT  = (ushort_t*)(ws + 10388480);
  ushort_t* WattnT = (ushort_t*)(ws + 10421248);
  ushort_t* WoutT  = (ushort_t*)(ws + 10454016);
  ushort_t* WcopyT = (ushort_t*)(ws + 10519552);
  unsigned* Upk2E  = (unsigned*)(ws + 10552320);
  unsigned* Upk2D  = (unsigned*)(ws + 10683392);
  ushort_t* encObf = (ushort_t*)(ws + 10814464);
  ushort_t* ehcbf  = (ushort_t*)(ws + 11879424);
  float*    h0c0   = ws + 11887616;

  float* sh  = out + (size_t)B_ * T_ * VO_;
  float* scf = sh + B_ * HD_;

  hipMemsetAsync(rsum, 0, 512 * sizeof(float), stream);

  hipLaunchKernelGGL(prep_kernel, dim3(5952), dim3(256), 0, stream,
                     Wenc, Wdec, We2d, Wattn, Wout, Wcopy, Uenc, Udec, x, decx, emb,
                     WencT, WdecT, We2dT, WattnT, WoutT, WcopyT, Upk2E, Upk2D,
                     xembbf, dembbf);

  hipLaunchKernelGGL(mfma_gemm, dim3(16, 128), dim3(256), 0, stream,
                     xembbf, WencT, benc, Xenc, (ushort_t*)nullptr, (float*)nullptr,
                     B_ * S_, 1024, 128, 1024, 0);
  hipLaunchKernelGGL(mfma_gemm, dim3(16, 8), dim3(256), 0, stream,
                     dembbf, WdecT, bdec, Xdec, (ushort_t*)nullptr, (float*)nullptr,
                     B_ * T_, 1024, 128, 1024, 0);

  // encoder: emits bf16 final states directly (ehcbf = [h | c])
  hipLaunchKernelGGL(lstm12, dim3(32), dim3(1024), 0, stream,
                     Xenc, Upk2E, (const float*)nullptr, (const float*)nullptr,
                     encObf, (float*)nullptr, (float*)nullptr,
                     ehcbf, ehcbf + 32 * 256, S_,
                     (const ushort_t*)nullptr, (const ushort_t*)nullptr,
                     (const float*)nullptr, (ushort_t*)nullptr);

  hipLaunchKernelGGL(mfma_gemm, dim3(4, 1), dim3(256), 0, stream,
                     ehcbf, We2dT, be2d, h0c0, (ushort_t*)nullptr, (float*)nullptr,
                     64, 256, 256, 256, 0);

  // decoder (32 lstm blocks) + Wcopy-GEMM role (128 blocks on idle CUs)
  hipLaunchKernelGGL(lstm12, dim3(32 + 128), dim3(1024), 0, stream,
                     Xdec, Upk2D, h0c0, h0c0 + 32 * 256, decObf, sh, scf,
                     (ushort_t*)nullptr, (ushort_t*)nullptr, T_,
                     encObf, WcopyT, bcopy, cp_bf);

  // attn: q = dec@Wattn fused in; writes catb directly
  hipLaunchKernelGGL(attn_kernel, dim3(B_ * T_), dim3(256), 0, stream,
                     decObf, WattnT, encObf, xlen, catb);
  hipLaunchKernelGGL(mfma_gemm, dim3(4, 8), dim3(256), 0, stream,
                     catb, WoutT, bout, (float*)nullptr, Abf, (float*)nullptr,
                     B_ * T_, 256, 512, 256, 1);
  // Wgen GEMM: reads f32 Wgen directly, transpose-on-the-fly into LDS
  hipLaunchKernelGGL(wgen_gemm, dim3(782), dim3(256), 0, stream,
                     Abf, Wgen, out, rsum);
  hipLaunchKernelGGL(copyseq_kernel, dim3(B_ * T_), dim3(256), 0, stream, Abf, cp_bf, xlen, cseq);
  hipLaunchKernelGGL(scatter_kernel, dim3(512), dim3(256), 0, stream, cseq, xoov, out, rsum);
  hipLaunchKernelGGL(rowlog_kernel, dim3(2), dim3(256), 0, stream, rsum, rowlog);
  hipLaunchKernelGGL(finalize_kernel, dim3((B_ * T_ * VO_ / 4 + 255) / 256), dim3(256), 0, stream,
                     out, rowlog);
}